// Round 1
// baseline (1935.025 us; speedup 1.0000x reference)
//
#include <hip/hip_runtime.h>
#include <math.h>

#define NIMG 800
#define T_DIM 128
#define N_DIM 100
#define D_DIM 256

// REC_LO[t] = DEC_LO[15-t];  REC_HI[t] = DEC_LO[t] * (-1)^t
__constant__ float c_RL[16] = {
     0.05441584224308161,   0.3128715909144659,    0.6756307362980128,    0.5853546836548691,
    -0.015829105256023893, -0.2840155429624281,    0.00047248457399797254,0.128747426620186,
    -0.01736930100202211,  -0.04408825393106472,   0.013981027917015516,  0.008746094047015655,
    -0.00487035299301066,  -0.0003917403729959771, 0.0006754494059985568, -0.00011747678400228192
};
__constant__ float c_RH[16] = {
    -0.00011747678400228192,-0.0006754494059985568,-0.0003917403729959771, 0.00487035299301066,
     0.008746094047015655,  -0.013981027917015516, -0.04408825393106472,   0.01736930100202211,
     0.128747426620186,     -0.00047248457399797254,-0.2840155429624281,   0.015829105256023893,
     0.5853546836548691,    -0.6756307362980128,    0.3128715909144659,   -0.05441584224308161
};

// Build combined 11x11 inception kernel: comb[oy+5][ox+5] = (1/6) * sum_{i >= max(|oy|,|ox|)} w_i[oy+i, ox+i]
__global__ void k_build_comb(const float* w0, const float* w1, const float* w2,
                             const float* w3, const float* w4, const float* w5,
                             const float* b0, const float* b1, const float* b2,
                             const float* b3, const float* b4, const float* b5,
                             float* comb)
{
    int t = threadIdx.x;
    const float* wp[6] = {w0, w1, w2, w3, w4, w5};
    if (t < 121) {
        int dy = t / 11 - 5, dx = t % 11 - 5;
        int ay = dy < 0 ? -dy : dy, ax = dx < 0 ? -dx : dx;
        int a = ay > ax ? ay : ax;
        float s = 0.f;
        for (int i = a; i < 6; ++i) {
            int k = 2 * i + 1;
            s += wp[i][(i + dy) * k + (i + dx)];
        }
        comb[t] = s * (1.0f / 6.0f);
    } else if (t == 121) {
        comb[121] = (b0[0] + b1[0] + b2[0] + b3[0] + b4[0] + b5[0]) * (1.0f / 6.0f);
    }
}

// Row (H-direction) DWT: Lp[img,i,c] = sum_t RL[t] * in[img, 2i+t-7, c] (zero-padded)
__global__ void k_dwt_rows(const float* __restrict__ in, float* __restrict__ Lp,
                           float* __restrict__ Hp, int H, int W, int level0)
{
    long idx = (long)blockIdx.x * blockDim.x + threadIdx.x;
    int h = H >> 1;
    long total = (long)NIMG * h * W;
    if (idx >= total) return;
    int c = (int)(idx % W);
    int i = (int)((idx / W) % h);
    int img = (int)(idx / ((long)W * h));
    const float* base; long rs;
    if (level0) {
        int bb = img / 100, nn = img - bb * 100;
        base = in + (long)bb * (T_DIM * N_DIM * D_DIM) + (long)nn * D_DIM + c;
        rs = (long)N_DIM * D_DIM;
    } else {
        base = in + (long)img * H * W + c;
        rs = W;
    }
    float sl = 0.f, sh = 0.f;
    int j0 = 2 * i - 7;
    #pragma unroll
    for (int t = 0; t < 16; ++t) {
        int j = j0 + t;
        if (j >= 0 && j < H) {
            float v = base[(long)j * rs];
            sl = fmaf(c_RL[t], v, sl);
            sh = fmaf(c_RH[t], v, sh);
        }
    }
    Lp[idx] = sl;
    Hp[idx] = sh;
}

// Column (W-direction) DWT from Lp/Hp -> 4 subbands
__global__ void k_dwt_cols(const float* __restrict__ Lp, const float* __restrict__ Hp,
                           float* __restrict__ LL, float* __restrict__ LH,
                           float* __restrict__ HL, float* __restrict__ HH,
                           int h, int W)
{
    int w = W >> 1;
    long idx = (long)blockIdx.x * blockDim.x + threadIdx.x;
    long total = (long)NIMG * h * w;
    if (idx >= total) return;
    int c = (int)(idx % w);
    int r = (int)((idx / w) % h);
    int img = (int)(idx / ((long)w * h));
    const float* lr = Lp + ((long)img * h + r) * W;
    const float* hr = Hp + ((long)img * h + r) * W;
    float ll = 0.f, lh = 0.f, hl = 0.f, hh = 0.f;
    int j0 = 2 * c - 7;
    #pragma unroll
    for (int t = 0; t < 16; ++t) {
        int j = j0 + t;
        if (j >= 0 && j < W) {
            float a = lr[j], b = hr[j];
            ll = fmaf(c_RL[t], a, ll);
            lh = fmaf(c_RH[t], a, lh);
            hl = fmaf(c_RL[t], b, hl);
            hh = fmaf(c_RH[t], b, hh);
        }
    }
    LL[idx] = ll;
    LH[idx] = lh;
    HL[idx] = hl;
    HH[idx] = hh;
}

// Per-row median-low of |HH|, scaled. One block per row, blockDim.x == w.
__global__ void k_median(const float* __restrict__ HH, float* __restrict__ thr,
                         int w, float scale)
{
    extern __shared__ float sm[];
    long row = blockIdx.x;
    const float* p = HH + row * w;
    int t = threadIdx.x;
    float v = fabsf(p[t]);
    sm[t] = v;
    __syncthreads();
    int k = (w - 1) >> 1;
    int lt = 0, eq = 0;
    for (int j = 0; j < w; ++j) {
        float u = sm[j];
        lt += (u < v) ? 1 : 0;
        eq += (u == v) ? 1 : 0;
    }
    if (lt <= k && k < lt + eq) thr[row] = v * scale;  // benign race: all writers write same value
}

// 11x11 zero-padded correlation with optional per-row soft-threshold on input.
__global__ __launch_bounds__(256) void k_incept(const float* __restrict__ in,
                                                const float* __restrict__ thr,
                                                const float* __restrict__ comb,
                                                float* __restrict__ out,
                                                int Hc, int Wc)
{
    __shared__ float tile[18 * 42];
    __shared__ float sc[122];
    int img = blockIdx.z;
    int y0 = blockIdx.y * 8, x0 = blockIdx.x * 32;
    const float* ip = in + (long)img * Hc * Wc;
    int tid = threadIdx.y * 32 + threadIdx.x;
    for (int s = tid; s < 18 * 42; s += 256) {
        int ly = s / 42, lx = s % 42;
        int gy = y0 + ly - 5, gx = x0 + lx - 5;
        float v = 0.f;
        if (gy >= 0 && gy < Hc && gx >= 0 && gx < Wc) {
            v = ip[(long)gy * Wc + gx];
            if (thr) {
                float th = thr[(long)img * Hc + gy];
                float m = fabsf(v) - th;
                v = (m > 0.f) ? copysignf(m, v) : 0.f;
            }
        }
        tile[s] = v;
    }
    for (int s = tid; s < 122; s += 256) sc[s] = comb[s];
    __syncthreads();
    int oy = y0 + threadIdx.y, ox = x0 + threadIdx.x;
    if (oy < Hc && ox < Wc) {
        float acc = sc[121];
        #pragma unroll
        for (int ky = 0; ky < 11; ++ky) {
            #pragma unroll
            for (int kx = 0; kx < 11; ++kx) {
                acc = fmaf(tile[(threadIdx.y + ky) * 42 + threadIdx.x + kx], sc[ky * 11 + kx], acc);
            }
        }
        out[(long)img * Hc * Wc + (long)oy * Wc + ox] = acc;
    }
}

// Inverse column transform: out[img,r,j] = sum over taps of RL[t]*A[img,r,i] + RH[t]*B[img,r,i], t = j-2i+7
__global__ void k_idwt_cols(const float* __restrict__ A, const float* __restrict__ B,
                            float* __restrict__ out, int h, int W)
{
    int w = W >> 1;
    long idx = (long)blockIdx.x * blockDim.x + threadIdx.x;
    long total = (long)NIMG * h * W;
    if (idx >= total) return;
    int c = (int)(idx % W);
    int r = (int)((idx / W) % h);
    int img = (int)(idx / ((long)W * h));
    const float* ar = A + ((long)img * h + r) * w;
    const float* br = B + ((long)img * h + r) * w;
    float s = 0.f;
    int t0 = (c & 1) ^ 1;
    #pragma unroll
    for (int t = t0; t < 16; t += 2) {
        int i = (c + 7 - t) >> 1;
        if (i >= 0 && i < w) {
            s = fmaf(c_RL[t], ar[i], s);
            s = fmaf(c_RH[t], br[i], s);
        }
    }
    out[idx] = s;
}

// Inverse row transform
__global__ void k_idwt_rows(const float* __restrict__ L, const float* __restrict__ Hh,
                            float* __restrict__ out, int H, int W)
{
    int h = H >> 1;
    long idx = (long)blockIdx.x * blockDim.x + threadIdx.x;
    long total = (long)NIMG * H * W;
    if (idx >= total) return;
    int c = (int)(idx % W);
    int j = (int)((idx / W) % H);
    int img = (int)(idx / ((long)W * H));
    const float* lb = L + (long)img * h * W + c;
    const float* hb = Hh + (long)img * h * W + c;
    float s = 0.f;
    int t0 = (j & 1) ^ 1;
    #pragma unroll
    for (int t = t0; t < 16; t += 2) {
        int i = (j + 7 - t) >> 1;
        if (i >= 0 && i < h) {
            s = fmaf(c_RL[t], lb[(long)i * W], s);
            s = fmaf(c_RH[t], hb[(long)i * W], s);
        }
    }
    out[idx] = s;
}

// Final GEMM: out[b,t,n,d] = sum_k A[(b*100+n)*128+t, k] * Wt[d,k] + bias[d]
__global__ __launch_bounds__(256) void k_out_gemm(const float* __restrict__ A,
                                                  const float* __restrict__ Wt,
                                                  const float* __restrict__ bias,
                                                  float* __restrict__ out)
{
    __shared__ float As[16][64];
    __shared__ float Bs[16][64];
    int m0 = blockIdx.x * 64, n0 = blockIdx.y * 64;
    int tid = threadIdx.x;
    int tm = (tid >> 4) * 4;
    int tn = (tid & 15) * 4;
    float acc[4][4] = {};
    for (int k0 = 0; k0 < 256; k0 += 16) {
        for (int s = tid; s < 1024; s += 256) {
            int mm = s >> 4, kk = s & 15;
            As[kk][mm] = A[(long)(m0 + mm) * 256 + (k0 + kk)];
        }
        for (int s = tid; s < 1024; s += 256) {
            int nn = s >> 4, kk = s & 15;
            Bs[kk][nn] = Wt[(long)(n0 + nn) * 256 + (k0 + kk)];
        }
        __syncthreads();
        #pragma unroll
        for (int kk = 0; kk < 16; ++kk) {
            float a0 = As[kk][tm], a1 = As[kk][tm + 1], a2 = As[kk][tm + 2], a3 = As[kk][tm + 3];
            float v0 = Bs[kk][tn], v1 = Bs[kk][tn + 1], v2 = Bs[kk][tn + 2], v3 = Bs[kk][tn + 3];
            acc[0][0] = fmaf(a0, v0, acc[0][0]); acc[0][1] = fmaf(a0, v1, acc[0][1]);
            acc[0][2] = fmaf(a0, v2, acc[0][2]); acc[0][3] = fmaf(a0, v3, acc[0][3]);
            acc[1][0] = fmaf(a1, v0, acc[1][0]); acc[1][1] = fmaf(a1, v1, acc[1][1]);
            acc[1][2] = fmaf(a1, v2, acc[1][2]); acc[1][3] = fmaf(a1, v3, acc[1][3]);
            acc[2][0] = fmaf(a2, v0, acc[2][0]); acc[2][1] = fmaf(a2, v1, acc[2][1]);
            acc[2][2] = fmaf(a2, v2, acc[2][2]); acc[2][3] = fmaf(a2, v3, acc[2][3]);
            acc[3][0] = fmaf(a3, v0, acc[3][0]); acc[3][1] = fmaf(a3, v1, acc[3][1]);
            acc[3][2] = fmaf(a3, v2, acc[3][2]); acc[3][3] = fmaf(a3, v3, acc[3][3]);
        }
        __syncthreads();
    }
    #pragma unroll
    for (int r = 0; r < 4; ++r) {
        int m = m0 + tm + r;
        int img = m >> 7, t = m & 127;
        int bb = img / 100, nn = img - bb * 100;
        long ob = (((long)bb * T_DIM + t) * N_DIM + nn) * D_DIM;
        #pragma unroll
        for (int cc = 0; cc < 4; ++cc) {
            int d = n0 + tn + cc;
            out[ob + d] = acc[r][cc] + bias[d];
        }
    }
}

static inline int nblk(long n) { return (int)((n + 255) / 256); }

extern "C" void kernel_launch(void* const* d_in, const int* in_sizes, int n_in,
                              void* d_out, int out_size, void* d_ws, size_t ws_size,
                              hipStream_t stream)
{
    const float* x = (const float*)d_in[0];
    // d_in[1] = adj (unused by reference)
    const float* w0 = (const float*)d_in[2];  const float* b0 = (const float*)d_in[3];
    const float* w1 = (const float*)d_in[4];  const float* b1 = (const float*)d_in[5];
    const float* w2 = (const float*)d_in[6];  const float* b2 = (const float*)d_in[7];
    const float* w3 = (const float*)d_in[8];  const float* b3 = (const float*)d_in[9];
    const float* w4 = (const float*)d_in[10]; const float* b4 = (const float*)d_in[11];
    const float* w5 = (const float*)d_in[12]; const float* b5 = (const float*)d_in[13];
    const float* out_w = (const float*)d_in[14];
    const float* out_b = (const float*)d_in[15];
    float* ws = (float*)d_ws;
    float* outp = (float*)d_out;

    const long S0 = 6553600, S1 = 1638400, S2 = 409600;
    const long RT = 13107200, FI = 26214400;

    float* pLH[3] = { ws,               ws + 3 * S0,           ws + 3 * S0 + 3 * S1 };
    float* pHL[3] = { ws + S0,          ws + 3 * S0 + S1,      ws + 3 * S0 + 3 * S1 + S2 };
    float* pHH[3] = { ws + 2 * S0,      ws + 3 * S0 + 2 * S1,  ws + 3 * S0 + 3 * S1 + 2 * S2 };
    float* pLL2 = ws + 3 * S0 + 3 * S1 + 3 * S2;
    float* comb = ws + 3 * S0 + 3 * S1 + 4 * S2;
    float* thr  = comb + 128;
    float* LLa  = thr + 51200;
    float* LLb  = LLa + S0;
    float* bufA = LLb + S1;
    float* bufB = bufA + RT;
    float* bufLL = bufB + RT;
    (void)ws_size; (void)in_sizes; (void)n_in; (void)out_size; (void)FI;

    hipLaunchKernelGGL(k_build_comb, dim3(1), dim3(128), 0, stream,
                       w0, w1, w2, w3, w4, w5, b0, b1, b2, b3, b4, b5, comb);

    float thr_scale = (float)(sqrt(2.0 * log(128.0)) / 0.6745);

    int Hs[3] = {128, 64, 32}, Ws3[3] = {256, 128, 64};
    const float* curLL = x;
    float* convLLout[3] = { LLa, LLb, pLL2 };

    for (int lev = 0; lev < 3; ++lev) {
        int H = Hs[lev], W = Ws3[lev], h = H >> 1, w = W >> 1;
        long nrow = (long)NIMG * h * W;
        hipLaunchKernelGGL(k_dwt_rows, dim3(nblk(nrow)), dim3(256), 0, stream,
                           curLL, bufA, bufB, H, W, lev == 0 ? 1 : 0);
        long S = (long)NIMG * h * w;
        float* rLL = bufLL;
        float* rLH = bufLL + S;
        float* rHL = bufLL + 2 * S;
        float* rHH = bufLL + 3 * S;
        hipLaunchKernelGGL(k_dwt_cols, dim3(nblk(S)), dim3(256), 0, stream,
                           bufA, bufB, rLL, rLH, rHL, rHH, h, W);
        hipLaunchKernelGGL(k_median, dim3(NIMG * h), dim3(w), w * sizeof(float), stream,
                           rHH, thr, w, thr_scale);
        dim3 cg(w / 32, h / 8, NIMG);
        dim3 cb(32, 8);
        hipLaunchKernelGGL(k_incept, cg, cb, 0, stream, rLL, (const float*)nullptr, comb, convLLout[lev], h, w);
        hipLaunchKernelGGL(k_incept, cg, cb, 0, stream, rLH, thr, comb, pLH[lev], h, w);
        hipLaunchKernelGGL(k_incept, cg, cb, 0, stream, rHL, thr, comb, pHL[lev], h, w);
        hipLaunchKernelGGL(k_incept, cg, cb, 0, stream, rHH, thr, comb, pHH[lev], h, w);
        curLL = convLLout[lev];
    }

    const float* LLcur = pLL2;
    for (int lev = 2; lev >= 0; --lev) {
        int H = Hs[lev], W = Ws3[lev], h = H >> 1;
        long nc = (long)NIMG * h * W;
        hipLaunchKernelGGL(k_idwt_cols, dim3(nblk(nc)), dim3(256), 0, stream,
                           LLcur, pLH[lev], bufA, h, W);
        hipLaunchKernelGGL(k_idwt_cols, dim3(nblk(nc)), dim3(256), 0, stream,
                           pHL[lev], pHH[lev], bufB, h, W);
        long nr = (long)NIMG * H * W;
        hipLaunchKernelGGL(k_idwt_rows, dim3(nblk(nr)), dim3(256), 0, stream,
                           bufA, bufB, bufLL, H, W);
        LLcur = bufLL;
    }

    dim3 gg(102400 / 64, 256 / 64);
    hipLaunchKernelGGL(k_out_gemm, gg, dim3(256), 0, stream, bufLL, out_w, out_b, outp);
}

// Round 2
// 1812.510 us; speedup vs baseline: 1.0676x; 1.0676x over previous
//
#include <hip/hip_runtime.h>
#include <math.h>

#define NIMG 800
#define T_DIM 128
#define N_DIM 100
#define D_DIM 256

typedef unsigned short ushort_t;
typedef unsigned int uint_t;
typedef __attribute__((ext_vector_type(8))) short short8;
typedef __attribute__((ext_vector_type(4))) float f32x4;

// REC_LO[t] = DEC_LO[15-t];  REC_HI[t] = DEC_LO[t] * (-1)^t
__constant__ float c_RL[16] = {
     0.05441584224308161,   0.3128715909144659,    0.6756307362980128,    0.5853546836548691,
    -0.015829105256023893, -0.2840155429624281,    0.00047248457399797254,0.128747426620186,
    -0.01736930100202211,  -0.04408825393106472,   0.013981027917015516,  0.008746094047015655,
    -0.00487035299301066,  -0.0003917403729959771, 0.0006754494059985568, -0.00011747678400228192
};
__constant__ float c_RH[16] = {
    -0.00011747678400228192,-0.0006754494059985568,-0.0003917403729959771, 0.00487035299301066,
     0.008746094047015655,  -0.013981027917015516, -0.04408825393106472,   0.01736930100202211,
     0.128747426620186,     -0.00047248457399797254,-0.2840155429624281,   0.015829105256023893,
     0.5853546836548691,    -0.6756307362980128,    0.3128715909144659,   -0.05441584224308161
};

__device__ inline ushort_t f2bf(float f) {
    uint_t u = __float_as_uint(f);
    uint_t r = (u + 0x7FFFu + ((u >> 16) & 1u)) >> 16;
    return (ushort_t)r;
}

// Build combined 11x11 inception kernel
__global__ void k_build_comb(const float* w0, const float* w1, const float* w2,
                             const float* w3, const float* w4, const float* w5,
                             const float* b0, const float* b1, const float* b2,
                             const float* b3, const float* b4, const float* b5,
                             float* comb)
{
    int t = threadIdx.x;
    const float* wp[6] = {w0, w1, w2, w3, w4, w5};
    if (t < 121) {
        int dy = t / 11 - 5, dx = t % 11 - 5;
        int ay = dy < 0 ? -dy : dy, ax = dx < 0 ? -dx : dx;
        int a = ay > ax ? ay : ax;
        float s = 0.f;
        for (int i = a; i < 6; ++i) {
            int k = 2 * i + 1;
            s += wp[i][(i + dy) * k + (i + dx)];
        }
        comb[t] = s * (1.0f / 6.0f);
    } else if (t == 121) {
        comb[121] = (b0[0] + b1[0] + b2[0] + b3[0] + b4[0] + b5[0]) * (1.0f / 6.0f);
    }
}

__global__ void k_cvt_bf16(const float* __restrict__ in, ushort_t* __restrict__ out, int n)
{
    int i = blockIdx.x * blockDim.x + threadIdx.x;
    if (i < n) out[i] = f2bf(in[i]);
}

// Row (H-direction) DWT
__global__ void k_dwt_rows(const float* __restrict__ in, float* __restrict__ Lp,
                           float* __restrict__ Hp, int H, int W, int level0)
{
    long idx = (long)blockIdx.x * blockDim.x + threadIdx.x;
    int h = H >> 1;
    long total = (long)NIMG * h * W;
    if (idx >= total) return;
    int c = (int)(idx % W);
    int i = (int)((idx / W) % h);
    int img = (int)(idx / ((long)W * h));
    const float* base; long rs;
    if (level0) {
        int bb = img / 100, nn = img - bb * 100;
        base = in + (long)bb * (T_DIM * N_DIM * D_DIM) + (long)nn * D_DIM + c;
        rs = (long)N_DIM * D_DIM;
    } else {
        base = in + (long)img * H * W + c;
        rs = W;
    }
    float sl = 0.f, sh = 0.f;
    int j0 = 2 * i - 7;
    #pragma unroll
    for (int t = 0; t < 16; ++t) {
        int j = j0 + t;
        if (j >= 0 && j < H) {
            float v = base[(long)j * rs];
            sl = fmaf(c_RL[t], v, sl);
            sh = fmaf(c_RH[t], v, sh);
        }
    }
    Lp[idx] = sl;
    Hp[idx] = sh;
}

// Column (W-direction) DWT
__global__ void k_dwt_cols(const float* __restrict__ Lp, const float* __restrict__ Hp,
                           float* __restrict__ LL, float* __restrict__ LH,
                           float* __restrict__ HL, float* __restrict__ HH,
                           int h, int W)
{
    int w = W >> 1;
    long idx = (long)blockIdx.x * blockDim.x + threadIdx.x;
    long total = (long)NIMG * h * w;
    if (idx >= total) return;
    int c = (int)(idx % w);
    int r = (int)((idx / w) % h);
    int img = (int)(idx / ((long)w * h));
    const float* lr = Lp + ((long)img * h + r) * W;
    const float* hr = Hp + ((long)img * h + r) * W;
    float ll = 0.f, lh = 0.f, hl = 0.f, hh = 0.f;
    int j0 = 2 * c - 7;
    #pragma unroll
    for (int t = 0; t < 16; ++t) {
        int j = j0 + t;
        if (j >= 0 && j < W) {
            float a = lr[j], b = hr[j];
            ll = fmaf(c_RL[t], a, ll);
            lh = fmaf(c_RH[t], a, lh);
            hl = fmaf(c_RL[t], b, hl);
            hh = fmaf(c_RH[t], b, hh);
        }
    }
    LL[idx] = ll;
    LH[idx] = lh;
    HL[idx] = hl;
    HH[idx] = hh;
}

// Per-row median-low of |HH|, scaled.
__global__ void k_median(const float* __restrict__ HH, float* __restrict__ thr,
                         int w, float scale)
{
    extern __shared__ float sm[];
    long row = blockIdx.x;
    const float* p = HH + row * w;
    int t = threadIdx.x;
    float v = fabsf(p[t]);
    sm[t] = v;
    __syncthreads();
    int k = (w - 1) >> 1;
    int lt = 0, eq = 0;
    for (int j = 0; j < w; ++j) {
        float u = sm[j];
        lt += (u < v) ? 1 : 0;
        eq += (u == v) ? 1 : 0;
    }
    if (lt <= k && k < lt + eq) thr[row] = v * scale;
}

// Sliding-window register conv: all 4 bands in one launch (grid.x = NIMG*4).
// Block = 256 threads = 4 waves; wave sid handles rows [sid*rps, (sid+1)*rps),
// each lane produces 2 consecutive x columns, acc[11][2] shift-register.
// Coefs come from uniform scalar loads (comb pointer + const offsets).
__global__ __launch_bounds__(256) void k_incept4(const float* __restrict__ bands,
    const float* __restrict__ thrp, const float* __restrict__ comb,
    float* __restrict__ oLL, float* __restrict__ oLH,
    float* __restrict__ oHL, float* __restrict__ oHH,
    int h, int w)
{
    int z = blockIdx.x;
    int band = z & 3, img = z >> 2;
    long S = (long)NIMG * h * w;
    const float* in = bands + (long)band * S + (long)img * h * w;
    float* outp = (band == 0 ? oLL : band == 1 ? oLH : band == 2 ? oHL : oHH)
                  + (long)img * h * w;
    const float* trow = (band == 0) ? (const float*)0 : (thrp + (long)img * h);
    int rps = h >> 2;
    int sid = threadIdx.x >> 6;
    int lane = threadIdx.x & 63;
    int x0 = 2 * lane;
    int ys = sid * rps;
    float cb = comb[121];

    // column clamp/validity (row-invariant)
    int xa[12]; bool okx[12];
    #pragma unroll
    for (int j = 0; j < 12; ++j) {
        int x = x0 - 5 + j;
        okx[j] = (x >= 0) && (x < w);
        xa[j] = x < 0 ? 0 : (x >= w ? w - 1 : x);
    }

    float acc[11][2];
    #pragma unroll
    for (int j = 0; j < 11; ++j) { acc[j][0] = 0.f; acc[j][1] = 0.f; }

    int nrow = rps + 10;
    for (int i = 0; i < nrow; ++i) {
        int gy = ys - 5 + i;
        float buf[12];
        if (gy >= 0 && gy < h) {
            const float* rp = in + (long)gy * w;
            if (trow) {
                float th = trow[gy];
                #pragma unroll
                for (int j = 0; j < 12; ++j) {
                    float v = rp[xa[j]];
                    float m = fabsf(v) - th;
                    v = (m > 0.f) ? copysignf(m, v) : 0.f;
                    buf[j] = okx[j] ? v : 0.f;
                }
            } else {
                #pragma unroll
                for (int j = 0; j < 12; ++j) {
                    float v = rp[xa[j]];
                    buf[j] = okx[j] ? v : 0.f;
                }
            }
        } else {
            #pragma unroll
            for (int j = 0; j < 12; ++j) buf[j] = 0.f;
        }
        // input row gy contributes with C-row ky to output row o = gy+5-ky (slot 10-ky)
        #pragma unroll
        for (int ky = 0; ky < 11; ++ky) {
            int jj = 10 - ky;
            #pragma unroll
            for (int kx = 0; kx < 11; ++kx) {
                float c = comb[ky * 11 + kx];   // uniform -> s_load
                acc[jj][0] = fmaf(buf[kx], c, acc[jj][0]);
                acc[jj][1] = fmaf(buf[kx + 1], c, acc[jj][1]);
            }
        }
        if (i >= 10 && x0 < w) {
            int oy = gy - 5;
            float2 st = make_float2(acc[0][0] + cb, acc[0][1] + cb);
            *(float2*)&outp[(long)oy * w + x0] = st;
        }
        #pragma unroll
        for (int j = 0; j < 10; ++j) { acc[j][0] = acc[j + 1][0]; acc[j][1] = acc[j + 1][1]; }
        acc[10][0] = 0.f; acc[10][1] = 0.f;
    }
}

// Inverse column transform
__global__ void k_idwt_cols(const float* __restrict__ A, const float* __restrict__ B,
                            float* __restrict__ out, int h, int W)
{
    int w = W >> 1;
    long idx = (long)blockIdx.x * blockDim.x + threadIdx.x;
    long total = (long)NIMG * h * W;
    if (idx >= total) return;
    int c = (int)(idx % W);
    int r = (int)((idx / W) % h);
    int img = (int)(idx / ((long)W * h));
    const float* ar = A + ((long)img * h + r) * w;
    const float* br = B + ((long)img * h + r) * w;
    float s = 0.f;
    int t0 = (c & 1) ^ 1;
    #pragma unroll
    for (int t = t0; t < 16; t += 2) {
        int i = (c + 7 - t) >> 1;
        if (i >= 0 && i < w) {
            s = fmaf(c_RL[t], ar[i], s);
            s = fmaf(c_RH[t], br[i], s);
        }
    }
    out[idx] = s;
}

// Inverse row transform; optional bf16 output (final level feeds the GEMM)
__global__ void k_idwt_rows(const float* __restrict__ L, const float* __restrict__ Hh,
                            float* __restrict__ out, ushort_t* __restrict__ outbf,
                            int H, int W)
{
    int h = H >> 1;
    long idx = (long)blockIdx.x * blockDim.x + threadIdx.x;
    long total = (long)NIMG * H * W;
    if (idx >= total) return;
    int c = (int)(idx % W);
    int j = (int)((idx / W) % H);
    int img = (int)(idx / ((long)W * H));
    const float* lb = L + (long)img * h * W + c;
    const float* hb = Hh + (long)img * h * W + c;
    float s = 0.f;
    int t0 = (j & 1) ^ 1;
    #pragma unroll
    for (int t = t0; t < 16; t += 2) {
        int i = (j + 7 - t) >> 1;
        if (i >= 0 && i < h) {
            s = fmaf(c_RL[t], lb[(long)i * W], s);
            s = fmaf(c_RH[t], hb[(long)i * W], s);
        }
    }
    if (outbf) outbf[idx] = f2bf(s);
    else out[idx] = s;
}

// bf16 MFMA GEMM: out[m,d] = sum_k A[m,k]*W[d,k] + bias[d], scattered to NCHW-ish layout.
// BM=BN=128, BK=64, 4 waves (2x2), 16x16x32 MFMA, XOR-swizzled LDS (16B chunk ^ row&7).
__global__ __launch_bounds__(256) void k_gemm_bf16(const ushort_t* __restrict__ A,
    const ushort_t* __restrict__ Bw, const float* __restrict__ bias,
    float* __restrict__ out)
{
    __shared__ uint4 Al4[128 * 8];
    __shared__ uint4 Bl4[128 * 8];
    int m0 = blockIdx.x * 128, n0 = blockIdx.y * 128;
    int tid = threadIdx.x;
    int wid = tid >> 6, lane = tid & 63;
    int wr = wid >> 1, wc = wid & 1;
    f32x4 acc[4][4];
    #pragma unroll
    for (int a = 0; a < 4; ++a)
        #pragma unroll
        for (int b = 0; b < 4; ++b)
            acc[a][b] = (f32x4){0.f, 0.f, 0.f, 0.f};

    const uint4* Ag = (const uint4*)A;   // one uint4 = 8 bf16
    const uint4* Bg = (const uint4*)Bw;
    int row = tid >> 1, half = tid & 1;

    for (int k0 = 0; k0 < 256; k0 += 64) {
        int gca = ((m0 + row) * 256 + k0 + half * 32) >> 3;
        int gcb = ((n0 + row) * 256 + k0 + half * 32) >> 3;
        #pragma unroll
        for (int q = 0; q < 4; ++q) {
            int c = half * 4 + q;
            int sw = c ^ (row & 7);
            Al4[row * 8 + sw] = Ag[gca + q];
            Bl4[row * 8 + sw] = Bg[gcb + q];
        }
        __syncthreads();
        #pragma unroll
        for (int ks = 0; ks < 2; ++ks) {
            short8 af[4], bfr[4];
            int kc = ks * 4 + (lane >> 4);
            #pragma unroll
            for (int mi = 0; mi < 4; ++mi) {
                int r = wr * 64 + mi * 16 + (lane & 15);
                af[mi] = *(const short8*)&Al4[r * 8 + (kc ^ (r & 7))];
            }
            #pragma unroll
            for (int ni = 0; ni < 4; ++ni) {
                int r = wc * 64 + ni * 16 + (lane & 15);
                bfr[ni] = *(const short8*)&Bl4[r * 8 + (kc ^ (r & 7))];
            }
            #pragma unroll
            for (int mi = 0; mi < 4; ++mi)
                #pragma unroll
                for (int ni = 0; ni < 4; ++ni)
                    acc[mi][ni] = __builtin_amdgcn_mfma_f32_16x16x32_bf16(
                        af[mi], bfr[ni], acc[mi][ni], 0, 0, 0);
        }
        __syncthreads();
    }

    #pragma unroll
    for (int ni = 0; ni < 4; ++ni) {
        int d = n0 + wc * 64 + ni * 16 + (lane & 15);
        float bv = bias[d];
        #pragma unroll
        for (int mi = 0; mi < 4; ++mi) {
            #pragma unroll
            for (int r = 0; r < 4; ++r) {
                int m = m0 + wr * 64 + mi * 16 + (lane >> 4) * 4 + r;
                int img = m >> 7, t = m & 127;
                int bb = img / 100, nn = img - bb * 100;
                long ob = (((long)bb * T_DIM + t) * N_DIM + nn) * D_DIM + d;
                out[ob] = acc[mi][ni][r] + bv;
            }
        }
    }
}

static inline int nblk(long n) { return (int)((n + 255) / 256); }

extern "C" void kernel_launch(void* const* d_in, const int* in_sizes, int n_in,
                              void* d_out, int out_size, void* d_ws, size_t ws_size,
                              hipStream_t stream)
{
    const float* x = (const float*)d_in[0];
    const float* w0 = (const float*)d_in[2];  const float* b0 = (const float*)d_in[3];
    const float* w1 = (const float*)d_in[4];  const float* b1 = (const float*)d_in[5];
    const float* w2 = (const float*)d_in[6];  const float* b2 = (const float*)d_in[7];
    const float* w3 = (const float*)d_in[8];  const float* b3 = (const float*)d_in[9];
    const float* w4 = (const float*)d_in[10]; const float* b4 = (const float*)d_in[11];
    const float* w5 = (const float*)d_in[12]; const float* b5 = (const float*)d_in[13];
    const float* out_w = (const float*)d_in[14];
    const float* out_b = (const float*)d_in[15];
    float* ws = (float*)d_ws;
    float* outp = (float*)d_out;

    const long S0 = 6553600, S1 = 1638400, S2 = 409600;
    const long RT = 13107200;

    float* pLH[3] = { ws,               ws + 3 * S0,           ws + 3 * S0 + 3 * S1 };
    float* pHL[3] = { ws + S0,          ws + 3 * S0 + S1,      ws + 3 * S0 + 3 * S1 + S2 };
    float* pHH[3] = { ws + 2 * S0,      ws + 3 * S0 + 2 * S1,  ws + 3 * S0 + 3 * S1 + 2 * S2 };
    float* pLL2 = ws + 3 * S0 + 3 * S1 + 3 * S2;
    float* comb = ws + 3 * S0 + 3 * S1 + 4 * S2;
    float* thr  = comb + 128;
    float* wbf_f = thr + 51200;             // 65536 bf16 = 32768 floats
    float* LLa  = wbf_f + 32768;
    float* LLb  = LLa + S0;
    float* bufA = LLb + S1;
    float* bufB = bufA + RT;
    float* bufLL = bufB + RT;
    ushort_t* wbf = (ushort_t*)wbf_f;
    ushort_t* Abf = (ushort_t*)bufLL;       // final idwt output in bf16 (52 MB < 105 MB region)
    (void)ws_size; (void)in_sizes; (void)n_in; (void)out_size;

    hipLaunchKernelGGL(k_build_comb, dim3(1), dim3(128), 0, stream,
                       w0, w1, w2, w3, w4, w5, b0, b1, b2, b3, b4, b5, comb);
    hipLaunchKernelGGL(k_cvt_bf16, dim3(256), dim3(256), 0, stream, out_w, wbf, 65536);

    float thr_scale = (float)(sqrt(2.0 * log(128.0)) / 0.6745);

    int Hs[3] = {128, 64, 32}, Ws3[3] = {256, 128, 64};
    const float* curLL = x;
    float* convLLout[3] = { LLa, LLb, pLL2 };

    for (int lev = 0; lev < 3; ++lev) {
        int H = Hs[lev], W = Ws3[lev], h = H >> 1, w = W >> 1;
        long nrow = (long)NIMG * h * W;
        hipLaunchKernelGGL(k_dwt_rows, dim3(nblk(nrow)), dim3(256), 0, stream,
                           curLL, bufA, bufB, H, W, lev == 0 ? 1 : 0);
        long S = (long)NIMG * h * w;
        float* rLL = bufLL;
        float* rHH = bufLL + 3 * S;
        hipLaunchKernelGGL(k_dwt_cols, dim3(nblk(S)), dim3(256), 0, stream,
                           bufA, bufB, rLL, bufLL + S, bufLL + 2 * S, rHH, h, W);
        hipLaunchKernelGGL(k_median, dim3(NIMG * h), dim3(w), w * sizeof(float), stream,
                           rHH, thr, w, thr_scale);
        hipLaunchKernelGGL(k_incept4, dim3(NIMG * 4), dim3(256), 0, stream,
                           rLL, thr, comb, convLLout[lev], pLH[lev], pHL[lev], pHH[lev], h, w);
        curLL = convLLout[lev];
    }

    const float* LLcur = pLL2;
    for (int lev = 2; lev >= 0; --lev) {
        int H = Hs[lev], W = Ws3[lev], h = H >> 1;
        long nc = (long)NIMG * h * W;
        hipLaunchKernelGGL(k_idwt_cols, dim3(nblk(nc)), dim3(256), 0, stream,
                           LLcur, pLH[lev], bufA, h, W);
        hipLaunchKernelGGL(k_idwt_cols, dim3(nblk(nc)), dim3(256), 0, stream,
                           pHL[lev], pHH[lev], bufB, h, W);
        long nr = (long)NIMG * H * W;
        hipLaunchKernelGGL(k_idwt_rows, dim3(nblk(nr)), dim3(256), 0, stream,
                           bufA, bufB, bufLL, (lev == 0) ? Abf : (ushort_t*)0, H, W);
        LLcur = bufLL;
    }

    dim3 gg(102400 / 128, 2);
    hipLaunchKernelGGL(k_gemm_bf16, gg, dim3(256), 0, stream, Abf, wbf, out_b, outp);
}

// Round 3
// 1548.529 us; speedup vs baseline: 1.2496x; 1.1705x over previous
//
#include <hip/hip_runtime.h>
#include <math.h>

#define NIMG 800
#define T_DIM 128
#define N_DIM 100
#define D_DIM 256

typedef unsigned short ushort_t;
typedef unsigned int uint_t;
typedef __attribute__((ext_vector_type(8))) short short8;
typedef __attribute__((ext_vector_type(4))) float f32x4;

// REC_LO[t] = DEC_LO[15-t];  REC_HI[t] = DEC_LO[t] * (-1)^t
__constant__ float c_RL[16] = {
     0.05441584224308161,   0.3128715909144659,    0.6756307362980128,    0.5853546836548691,
    -0.015829105256023893, -0.2840155429624281,    0.00047248457399797254,0.128747426620186,
    -0.01736930100202211,  -0.04408825393106472,   0.013981027917015516,  0.008746094047015655,
    -0.00487035299301066,  -0.0003917403729959771, 0.0006754494059985568, -0.00011747678400228192
};
__constant__ float c_RH[16] = {
    -0.00011747678400228192,-0.0006754494059985568,-0.0003917403729959771, 0.00487035299301066,
     0.008746094047015655,  -0.013981027917015516, -0.04408825393106472,   0.01736930100202211,
     0.128747426620186,     -0.00047248457399797254,-0.2840155429624281,   0.015829105256023893,
     0.5853546836548691,    -0.6756307362980128,    0.3128715909144659,   -0.05441584224308161
};

__device__ inline ushort_t f2bf(float f) {
    uint_t u = __float_as_uint(f);
    uint_t r = (u + 0x7FFFu + ((u >> 16) & 1u)) >> 16;
    return (ushort_t)r;
}

// Build combined 11x11 inception kernel
__global__ void k_build_comb(const float* w0, const float* w1, const float* w2,
                             const float* w3, const float* w4, const float* w5,
                             const float* b0, const float* b1, const float* b2,
                             const float* b3, const float* b4, const float* b5,
                             float* comb)
{
    int t = threadIdx.x;
    const float* wp[6] = {w0, w1, w2, w3, w4, w5};
    if (t < 121) {
        int dy = t / 11 - 5, dx = t % 11 - 5;
        int ay = dy < 0 ? -dy : dy, ax = dx < 0 ? -dx : dx;
        int a = ay > ax ? ay : ax;
        float s = 0.f;
        for (int i = a; i < 6; ++i) {
            int k = 2 * i + 1;
            s += wp[i][(i + dy) * k + (i + dx)];
        }
        comb[t] = s * (1.0f / 6.0f);
    } else if (t == 121) {
        comb[121] = (b0[0] + b1[0] + b2[0] + b3[0] + b4[0] + b5[0]) * (1.0f / 6.0f);
    }
}

__global__ void k_cvt_bf16(const float* __restrict__ in, ushort_t* __restrict__ out, int n)
{
    int i = blockIdx.x * blockDim.x + threadIdx.x;
    if (i < n) out[i] = f2bf(in[i]);
}

// Row (H-direction) DWT
__global__ void k_dwt_rows(const float* __restrict__ in, float* __restrict__ Lp,
                           float* __restrict__ Hp, int H, int W, int level0)
{
    long idx = (long)blockIdx.x * blockDim.x + threadIdx.x;
    int h = H >> 1;
    long total = (long)NIMG * h * W;
    if (idx >= total) return;
    int c = (int)(idx % W);
    int i = (int)((idx / W) % h);
    int img = (int)(idx / ((long)W * h));
    const float* base; long rs;
    if (level0) {
        int bb = img / 100, nn = img - bb * 100;
        base = in + (long)bb * (T_DIM * N_DIM * D_DIM) + (long)nn * D_DIM + c;
        rs = (long)N_DIM * D_DIM;
    } else {
        base = in + (long)img * H * W + c;
        rs = W;
    }
    float sl = 0.f, sh = 0.f;
    int j0 = 2 * i - 7;
    #pragma unroll
    for (int t = 0; t < 16; ++t) {
        int j = j0 + t;
        if (j >= 0 && j < H) {
            float v = base[(long)j * rs];
            sl = fmaf(c_RL[t], v, sl);
            sh = fmaf(c_RH[t], v, sh);
        }
    }
    Lp[idx] = sl;
    Hp[idx] = sh;
}

// Column (W-direction) DWT
__global__ void k_dwt_cols(const float* __restrict__ Lp, const float* __restrict__ Hp,
                           float* __restrict__ LL, float* __restrict__ LH,
                           float* __restrict__ HL, float* __restrict__ HH,
                           int h, int W)
{
    int w = W >> 1;
    long idx = (long)blockIdx.x * blockDim.x + threadIdx.x;
    long total = (long)NIMG * h * w;
    if (idx >= total) return;
    int c = (int)(idx % w);
    int r = (int)((idx / w) % h);
    int img = (int)(idx / ((long)w * h));
    const float* lr = Lp + ((long)img * h + r) * W;
    const float* hr = Hp + ((long)img * h + r) * W;
    float ll = 0.f, lh = 0.f, hl = 0.f, hh = 0.f;
    int j0 = 2 * c - 7;
    #pragma unroll
    for (int t = 0; t < 16; ++t) {
        int j = j0 + t;
        if (j >= 0 && j < W) {
            float a = lr[j], b = hr[j];
            ll = fmaf(c_RL[t], a, ll);
            lh = fmaf(c_RH[t], a, lh);
            hl = fmaf(c_RL[t], b, hl);
            hh = fmaf(c_RH[t], b, hh);
        }
    }
    LL[idx] = ll;
    LH[idx] = lh;
    HL[idx] = hl;
    HH[idx] = hh;
}

// Per-row median-low of |HH|: block=256 covers 256/w rows, padded LDS slices.
__global__ __launch_bounds__(256) void k_median256(const float* __restrict__ HH,
    float* __restrict__ thr, int w, int wsh, float scale)
{
    __shared__ float sm[256 + 8];
    int tid = threadIdx.x;
    int rloc = tid >> wsh;
    int j = tid & (w - 1);
    int rpb = 256 >> wsh;
    long row = (long)blockIdx.x * rpb + rloc;
    float v = fabsf(HH[row * w + j]);
    sm[rloc * (w + 1) + j] = v;
    __syncthreads();
    int k = (w - 1) >> 1;
    const float* base = sm + rloc * (w + 1);
    int lt = 0, eq = 0;
    for (int i = 0; i < w; ++i) {
        float u = base[i];
        lt += (u < v) ? 1 : 0;
        eq += (u == v) ? 1 : 0;
    }
    if (lt <= k && k < lt + eq) thr[row] = v * scale;
}

// Sliding-window register conv v2: thread = (img, band, row-half, col-quad).
// 4 output cols per lane, acc[11][4] shift register, branchless soft-threshold
// (th=0 for LL band), no idle lanes at any level.
__global__ __launch_bounds__(256) void k_incept_v2(const float* __restrict__ bands,
    const float* __restrict__ thrp, const float* __restrict__ comb,
    float* __restrict__ oLL, float* __restrict__ oLH,
    float* __restrict__ oHL, float* __restrict__ oHH,
    int h, int w, int nq_sh)
{
    int t = blockIdx.x * 256 + threadIdx.x;
    int q = t & ((1 << nq_sh) - 1);
    int rest = t >> nq_sh;
    int strip = rest & 1;
    int bi = rest >> 1;
    int band = bi & 3;
    int img = bi >> 2;
    long S = (long)NIMG * h * w;
    const float* in = bands + (long)band * S + (long)img * h * w;
    float* outp = (band == 0 ? oLL : band == 1 ? oLH : band == 2 ? oHL : oHH)
                  + (long)img * h * w;
    const float* trow = thrp + (long)img * h;
    float tmul = (band == 0) ? 0.f : 1.f;
    int rp2 = h >> 1;
    int ys = strip * rp2;
    int x0 = q << 2;
    float cb = comb[121];

    float okm[14]; int xa[14];
    #pragma unroll
    for (int j = 0; j < 14; ++j) {
        int x = x0 - 5 + j;
        okm[j] = (x >= 0 && x < w) ? 1.f : 0.f;
        xa[j] = (x < 0) ? 0 : ((x >= w) ? (w - 1) : x);
    }

    float acc[11][4];
    #pragma unroll
    for (int j = 0; j < 11; ++j) {
        acc[j][0] = 0.f; acc[j][1] = 0.f; acc[j][2] = 0.f; acc[j][3] = 0.f;
    }

    const float* rp = in + (long)(ys - 5) * w;
    int nrow = rp2 + 10;
    for (int i = 0; i < nrow; ++i) {
        int gy = ys - 5 + i;
        float buf[14];
        if (gy >= 0 && gy < h) {
            float th = trow[gy] * tmul;
            #pragma unroll
            for (int j = 0; j < 14; ++j) {
                float v = rp[xa[j]];
                float m = fabsf(v) - th;
                v = (m > 0.f) ? copysignf(m, v) : 0.f;
                buf[j] = v * okm[j];
            }
        } else {
            #pragma unroll
            for (int j = 0; j < 14; ++j) buf[j] = 0.f;
        }
        #pragma unroll
        for (int ky = 0; ky < 11; ++ky) {
            int jj = 10 - ky;
            #pragma unroll
            for (int kx = 0; kx < 11; ++kx) {
                float c = comb[ky * 11 + kx];
                acc[jj][0] = fmaf(buf[kx],     c, acc[jj][0]);
                acc[jj][1] = fmaf(buf[kx + 1], c, acc[jj][1]);
                acc[jj][2] = fmaf(buf[kx + 2], c, acc[jj][2]);
                acc[jj][3] = fmaf(buf[kx + 3], c, acc[jj][3]);
            }
        }
        if (i >= 10) {
            int oy = gy - 5;
            float4 st = make_float4(acc[0][0] + cb, acc[0][1] + cb,
                                    acc[0][2] + cb, acc[0][3] + cb);
            *(float4*)&outp[(long)oy * w + x0] = st;
        }
        #pragma unroll
        for (int j2 = 0; j2 < 10; ++j2) {
            acc[j2][0] = acc[j2 + 1][0]; acc[j2][1] = acc[j2 + 1][1];
            acc[j2][2] = acc[j2 + 1][2]; acc[j2][3] = acc[j2 + 1][3];
        }
        acc[10][0] = 0.f; acc[10][1] = 0.f; acc[10][2] = 0.f; acc[10][3] = 0.f;
        rp += w;
    }
}

// Inverse column transform
__global__ void k_idwt_cols(const float* __restrict__ A, const float* __restrict__ B,
                            float* __restrict__ out, int h, int W)
{
    int w = W >> 1;
    long idx = (long)blockIdx.x * blockDim.x + threadIdx.x;
    long total = (long)NIMG * h * W;
    if (idx >= total) return;
    int c = (int)(idx % W);
    int r = (int)((idx / W) % h);
    int img = (int)(idx / ((long)W * h));
    const float* ar = A + ((long)img * h + r) * w;
    const float* br = B + ((long)img * h + r) * w;
    float s = 0.f;
    int t0 = (c & 1) ^ 1;
    #pragma unroll
    for (int t = t0; t < 16; t += 2) {
        int i = (c + 7 - t) >> 1;
        if (i >= 0 && i < w) {
            s = fmaf(c_RL[t], ar[i], s);
            s = fmaf(c_RH[t], br[i], s);
        }
    }
    out[idx] = s;
}

// Inverse row transform; optional bf16 output (final level feeds the GEMM)
__global__ void k_idwt_rows(const float* __restrict__ L, const float* __restrict__ Hh,
                            float* __restrict__ out, ushort_t* __restrict__ outbf,
                            int H, int W)
{
    int h = H >> 1;
    long idx = (long)blockIdx.x * blockDim.x + threadIdx.x;
    long total = (long)NIMG * H * W;
    if (idx >= total) return;
    int c = (int)(idx % W);
    int j = (int)((idx / W) % H);
    int img = (int)(idx / ((long)W * H));
    const float* lb = L + (long)img * h * W + c;
    const float* hb = Hh + (long)img * h * W + c;
    float s = 0.f;
    int t0 = (j & 1) ^ 1;
    #pragma unroll
    for (int t = t0; t < 16; t += 2) {
        int i = (j + 7 - t) >> 1;
        if (i >= 0 && i < h) {
            s = fmaf(c_RL[t], lb[(long)i * W], s);
            s = fmaf(c_RH[t], hb[(long)i * W], s);
        }
    }
    if (outbf) outbf[idx] = f2bf(s);
    else out[idx] = s;
}

// bf16 MFMA GEMM: out[m,d] = sum_k A[m,k]*W[d,k] + bias[d], scattered output.
__global__ __launch_bounds__(256) void k_gemm_bf16(const ushort_t* __restrict__ A,
    const ushort_t* __restrict__ Bw, const float* __restrict__ bias,
    float* __restrict__ out)
{
    __shared__ uint4 Al4[128 * 8];
    __shared__ uint4 Bl4[128 * 8];
    int m0 = blockIdx.x * 128, n0 = blockIdx.y * 128;
    int tid = threadIdx.x;
    int wid = tid >> 6, lane = tid & 63;
    int wr = wid >> 1, wc = wid & 1;
    f32x4 acc[4][4];
    #pragma unroll
    for (int a = 0; a < 4; ++a)
        #pragma unroll
        for (int b = 0; b < 4; ++b)
            acc[a][b] = (f32x4){0.f, 0.f, 0.f, 0.f};

    const uint4* Ag = (const uint4*)A;
    const uint4* Bg = (const uint4*)Bw;
    int row = tid >> 1, half = tid & 1;

    for (int k0 = 0; k0 < 256; k0 += 64) {
        int gca = ((m0 + row) * 256 + k0 + half * 32) >> 3;
        int gcb = ((n0 + row) * 256 + k0 + half * 32) >> 3;
        #pragma unroll
        for (int q = 0; q < 4; ++q) {
            int c = half * 4 + q;
            int sw = c ^ (row & 7);
            Al4[row * 8 + sw] = Ag[gca + q];
            Bl4[row * 8 + sw] = Bg[gcb + q];
        }
        __syncthreads();
        #pragma unroll
        for (int ks = 0; ks < 2; ++ks) {
            short8 af[4], bfr[4];
            int kc = ks * 4 + (lane >> 4);
            #pragma unroll
            for (int mi = 0; mi < 4; ++mi) {
                int r = wr * 64 + mi * 16 + (lane & 15);
                af[mi] = *(const short8*)&Al4[r * 8 + (kc ^ (r & 7))];
            }
            #pragma unroll
            for (int ni = 0; ni < 4; ++ni) {
                int r = wc * 64 + ni * 16 + (lane & 15);
                bfr[ni] = *(const short8*)&Bl4[r * 8 + (kc ^ (r & 7))];
            }
            #pragma unroll
            for (int mi = 0; mi < 4; ++mi)
                #pragma unroll
                for (int ni = 0; ni < 4; ++ni)
                    acc[mi][ni] = __builtin_amdgcn_mfma_f32_16x16x32_bf16(
                        af[mi], bfr[ni], acc[mi][ni], 0, 0, 0);
        }
        __syncthreads();
    }

    #pragma unroll
    for (int ni = 0; ni < 4; ++ni) {
        int d = n0 + wc * 64 + ni * 16 + (lane & 15);
        float bv = bias[d];
        #pragma unroll
        for (int mi = 0; mi < 4; ++mi) {
            #pragma unroll
            for (int r = 0; r < 4; ++r) {
                int m = m0 + wr * 64 + mi * 16 + (lane >> 4) * 4 + r;
                int img = m >> 7, t = m & 127;
                int bb = img / 100, nn = img - bb * 100;
                long ob = (((long)bb * T_DIM + t) * N_DIM + nn) * D_DIM + d;
                out[ob] = acc[mi][ni][r] + bv;
            }
        }
    }
}

static inline int nblk(long n) { return (int)((n + 255) / 256); }

extern "C" void kernel_launch(void* const* d_in, const int* in_sizes, int n_in,
                              void* d_out, int out_size, void* d_ws, size_t ws_size,
                              hipStream_t stream)
{
    const float* x = (const float*)d_in[0];
    const float* w0 = (const float*)d_in[2];  const float* b0 = (const float*)d_in[3];
    const float* w1 = (const float*)d_in[4];  const float* b1 = (const float*)d_in[5];
    const float* w2 = (const float*)d_in[6];  const float* b2 = (const float*)d_in[7];
    const float* w3 = (const float*)d_in[8];  const float* b3 = (const float*)d_in[9];
    const float* w4 = (const float*)d_in[10]; const float* b4 = (const float*)d_in[11];
    const float* w5 = (const float*)d_in[12]; const float* b5 = (const float*)d_in[13];
    const float* out_w = (const float*)d_in[14];
    const float* out_b = (const float*)d_in[15];
    float* ws = (float*)d_ws;
    float* outp = (float*)d_out;

    const long S0 = 6553600, S1 = 1638400, S2 = 409600;
    const long RT = 13107200;

    float* pLH[3] = { ws,               ws + 3 * S0,           ws + 3 * S0 + 3 * S1 };
    float* pHL[3] = { ws + S0,          ws + 3 * S0 + S1,      ws + 3 * S0 + 3 * S1 + S2 };
    float* pHH[3] = { ws + 2 * S0,      ws + 3 * S0 + 2 * S1,  ws + 3 * S0 + 3 * S1 + 2 * S2 };
    float* pLL2 = ws + 3 * S0 + 3 * S1 + 3 * S2;
    float* comb = ws + 3 * S0 + 3 * S1 + 4 * S2;
    float* thr  = comb + 128;
    float* wbf_f = thr + 51200;
    float* LLa  = wbf_f + 32768;
    float* LLb  = LLa + S0;
    float* bufA = LLb + S1;
    float* bufB = bufA + RT;
    float* bufLL = bufB + RT;
    ushort_t* wbf = (ushort_t*)wbf_f;
    ushort_t* Abf = (ushort_t*)bufLL;
    (void)ws_size; (void)in_sizes; (void)n_in; (void)out_size;

    hipLaunchKernelGGL(k_build_comb, dim3(1), dim3(128), 0, stream,
                       w0, w1, w2, w3, w4, w5, b0, b1, b2, b3, b4, b5, comb);
    hipLaunchKernelGGL(k_cvt_bf16, dim3(256), dim3(256), 0, stream, out_w, wbf, 65536);

    float thr_scale = (float)(sqrt(2.0 * log(128.0)) / 0.6745);

    int Hs[3] = {128, 64, 32}, Ws3[3] = {256, 128, 64};
    int wsh3[3] = {7, 6, 5};      // log2(w) per level
    int nqsh3[3] = {5, 4, 3};     // log2(w/4) per level
    const float* curLL = x;
    float* convLLout[3] = { LLa, LLb, pLL2 };

    for (int lev = 0; lev < 3; ++lev) {
        int H = Hs[lev], W = Ws3[lev], h = H >> 1, w = W >> 1;
        long nrow = (long)NIMG * h * W;
        hipLaunchKernelGGL(k_dwt_rows, dim3(nblk(nrow)), dim3(256), 0, stream,
                           curLL, bufA, bufB, H, W, lev == 0 ? 1 : 0);
        long S = (long)NIMG * h * w;
        float* rLL = bufLL;
        float* rHH = bufLL + 3 * S;
        hipLaunchKernelGGL(k_dwt_cols, dim3(nblk(S)), dim3(256), 0, stream,
                           bufA, bufB, rLL, bufLL + S, bufLL + 2 * S, rHH, h, W);
        hipLaunchKernelGGL(k_median256, dim3((int)(S / 256)), dim3(256), 0, stream,
                           rHH, thr, w, wsh3[lev], thr_scale);
        int nthr = NIMG * 4 * 2 * (w / 4);
        hipLaunchKernelGGL(k_incept_v2, dim3(nthr / 256), dim3(256), 0, stream,
                           rLL, thr, comb, convLLout[lev], pLH[lev], pHL[lev], pHH[lev],
                           h, w, nqsh3[lev]);
        curLL = convLLout[lev];
    }

    const float* LLcur = pLL2;
    for (int lev = 2; lev >= 0; --lev) {
        int H = Hs[lev], W = Ws3[lev], h = H >> 1;
        long nc = (long)NIMG * h * W;
        hipLaunchKernelGGL(k_idwt_cols, dim3(nblk(nc)), dim3(256), 0, stream,
                           LLcur, pLH[lev], bufA, h, W);
        hipLaunchKernelGGL(k_idwt_cols, dim3(nblk(nc)), dim3(256), 0, stream,
                           pHL[lev], pHH[lev], bufB, h, W);
        long nr = (long)NIMG * H * W;
        hipLaunchKernelGGL(k_idwt_rows, dim3(nblk(nr)), dim3(256), 0, stream,
                           bufA, bufB, bufLL, (lev == 0) ? Abf : (ushort_t*)0, H, W);
        LLcur = bufLL;
    }

    dim3 gg(102400 / 128, 2);
    hipLaunchKernelGGL(k_gemm_bf16, gg, dim3(256), 0, stream, Abf, wbf, out_b, outp);
}

// Round 4
// 1317.745 us; speedup vs baseline: 1.4684x; 1.1751x over previous
//
#include <hip/hip_runtime.h>
#include <math.h>

#define NIMG 800
#define T_DIM 128
#define N_DIM 100
#define D_DIM 256

typedef unsigned short ushort_t;
typedef unsigned int uint_t;
typedef __attribute__((ext_vector_type(8))) short short8;
typedef __attribute__((ext_vector_type(4))) float f32x4;

// REC_LO[t] = DEC_LO[15-t];  REC_HI[t] = DEC_LO[t] * (-1)^t
__constant__ float c_RL[16] = {
     0.05441584224308161,   0.3128715909144659,    0.6756307362980128,    0.5853546836548691,
    -0.015829105256023893, -0.2840155429624281,    0.00047248457399797254,0.128747426620186,
    -0.01736930100202211,  -0.04408825393106472,   0.013981027917015516,  0.008746094047015655,
    -0.00487035299301066,  -0.0003917403729959771, 0.0006754494059985568, -0.00011747678400228192
};
__constant__ float c_RH[16] = {
    -0.00011747678400228192,-0.0006754494059985568,-0.0003917403729959771, 0.00487035299301066,
     0.008746094047015655,  -0.013981027917015516, -0.04408825393106472,   0.01736930100202211,
     0.128747426620186,     -0.00047248457399797254,-0.2840155429624281,   0.015829105256023893,
     0.5853546836548691,    -0.6756307362980128,    0.3128715909144659,   -0.05441584224308161
};

__device__ inline ushort_t f2bf(float f) {
    uint_t u = __float_as_uint(f);
    uint_t r = (u + 0x7FFFu + ((u >> 16) & 1u)) >> 16;
    return (ushort_t)r;
}

// Build combined 11x11 inception kernel
__global__ void k_build_comb(const float* w0, const float* w1, const float* w2,
                             const float* w3, const float* w4, const float* w5,
                             const float* b0, const float* b1, const float* b2,
                             const float* b3, const float* b4, const float* b5,
                             float* comb)
{
    int t = threadIdx.x;
    const float* wp[6] = {w0, w1, w2, w3, w4, w5};
    if (t < 121) {
        int dy = t / 11 - 5, dx = t % 11 - 5;
        int ay = dy < 0 ? -dy : dy, ax = dx < 0 ? -dx : dx;
        int a = ay > ax ? ay : ax;
        float s = 0.f;
        for (int i = a; i < 6; ++i) {
            int k = 2 * i + 1;
            s += wp[i][(i + dy) * k + (i + dx)];
        }
        comb[t] = s * (1.0f / 6.0f);
    } else if (t == 121) {
        comb[121] = (b0[0] + b1[0] + b2[0] + b3[0] + b4[0] + b5[0]) * (1.0f / 6.0f);
    }
}

__global__ void k_cvt_bf16(const float* __restrict__ in, ushort_t* __restrict__ out, int n)
{
    int i = blockIdx.x * blockDim.x + threadIdx.x;
    if (i < n) out[i] = f2bf(in[i]);
}

// Fused per-level 2D DWT: block = (img, output-col strip of Q).
// LDS: xs[H][CW] -> row-pass Lp/Hp[h][CW] -> col-pass -> 4 subbands.
// CW = 2Q+16. Static LDS sized for worst case (L0: Q=32 -> 20480 floats).
__global__ __launch_bounds__(256) void k_dwt2d(const float* __restrict__ in,
    float* __restrict__ LL, float* __restrict__ LH,
    float* __restrict__ HL, float* __restrict__ HH,
    int H, int W, int Q, int level0)
{
    __shared__ float sm[20480];
    int h = H >> 1, w = W >> 1;
    int nstrips = w / Q;
    int img = blockIdx.x / nstrips;
    int q = blockIdx.x - img * nstrips;
    int q0 = q * Q;
    int c0 = 2 * q0 - 7;
    int CW = 2 * Q + 16;
    float* xs = sm;
    float* Lp = sm + H * CW;
    float* Hp = Lp + h * CW;
    int tid = threadIdx.x;

    const float* ip; long rstride;
    if (level0) {
        int bb = img / 100, nn = img - bb * 100;
        ip = in + (long)bb * (T_DIM * N_DIM * D_DIM) + (long)nn * D_DIM;
        rstride = (long)N_DIM * D_DIM;
    } else {
        ip = in + (long)img * H * W;
        rstride = W;
    }
    for (int s = tid; s < H * CW; s += 256) {
        int r = s / CW, c = s - r * CW;
        int gc = c0 + c;
        xs[s] = (gc >= 0 && gc < W) ? ip[(long)r * rstride + gc] : 0.f;
    }
    __syncthreads();
    // row pass (along H): Lp[i][c] = sum_t RL[t] * x[2i+t-7][c]
    for (int s = tid; s < h * CW; s += 256) {
        int i = s / CW, c = s - i * CW;
        float sl = 0.f, sh = 0.f;
        int j0 = 2 * i - 7;
        #pragma unroll
        for (int t = 0; t < 16; ++t) {
            int j = j0 + t;
            if (j >= 0 && j < H) {
                float v = xs[j * CW + c];
                sl = fmaf(c_RL[t], v, sl);
                sh = fmaf(c_RH[t], v, sh);
            }
        }
        Lp[s] = sl; Hp[s] = sh;
    }
    __syncthreads();
    // col pass (along W): out[r][cc] from Lp/Hp[r][2cc+t-7]
    for (int s = tid; s < h * Q; s += 256) {
        int r = s / Q, cl = s - r * Q;
        int cc = q0 + cl;
        float ll = 0.f, lh = 0.f, hl = 0.f, hh = 0.f;
        int j0 = 2 * cc - 7;
        #pragma unroll
        for (int t = 0; t < 16; ++t) {
            int j = j0 + t;
            if (j >= 0 && j < W) {
                int lc = j - c0;
                float a = Lp[r * CW + lc], b = Hp[r * CW + lc];
                ll = fmaf(c_RL[t], a, ll);
                lh = fmaf(c_RH[t], a, lh);
                hl = fmaf(c_RL[t], b, hl);
                hh = fmaf(c_RH[t], b, hh);
            }
        }
        long o = (long)img * h * w + (long)r * w + cc;
        LL[o] = ll; LH[o] = lh; HL[o] = hl; HH[o] = hh;
    }
}

// Fused per-level 2D iDWT: block = (img, output-col strip of Q=64).
// Stage 4 subband strips -> col-idwt L/Hh in LDS (full height) -> row-idwt -> out.
__global__ __launch_bounds__(256) void k_idwt2d(const float* __restrict__ LLp,
    const float* __restrict__ LHp, const float* __restrict__ HLp,
    const float* __restrict__ HHp, float* __restrict__ outp,
    ushort_t* __restrict__ outbf, int H, int W, int fin)
{
    const int Q = 64;
    __shared__ float sm[18432];
    int h = H >> 1, w = W >> 1;
    int nstrips = W / Q;
    int img = blockIdx.x / nstrips;
    int q = blockIdx.x - img * nstrips;
    int q0 = q * Q;
    int i0 = (q0 >> 1) - 4;
    int SW = (Q >> 1) + 8;   // 40
    float* sLL = sm;
    float* sLH = sLL + h * SW;
    float* sHL = sLH + h * SW;
    float* sHH = sHL + h * SW;
    float* sL  = sHH + h * SW;
    float* sH  = sL + h * Q;
    int tid = threadIdx.x;

    long ibase = (long)img * h * w;
    for (int s = tid; s < h * SW; s += 256) {
        int r = s / SW, c = s - r * SW;
        int gc = i0 + c;
        bool ok = (gc >= 0 && gc < w);
        long o = ibase + (long)r * w + gc;
        sLL[s] = ok ? LLp[o] : 0.f;
        sLH[s] = ok ? LHp[o] : 0.f;
        sHL[s] = ok ? HLp[o] : 0.f;
        sHH[s] = ok ? HHp[o] : 0.f;
    }
    __syncthreads();
    // col-idwt: L[r][c], Hh[r][c] for c in strip
    for (int s = tid; s < h * Q; s += 256) {
        int r = s / Q, cl = s - r * Q;
        int c = q0 + cl;
        float sl = 0.f, sh = 0.f;
        int t0 = (c & 1) ^ 1;
        #pragma unroll
        for (int t = t0; t < 16; t += 2) {
            int i = (c + 7 - t) >> 1;
            if (i >= 0 && i < w) {
                int lc = i - i0;
                float a = sLL[r * SW + lc], bq = sLH[r * SW + lc];
                float cc2 = sHL[r * SW + lc], d = sHH[r * SW + lc];
                sl = fmaf(c_RL[t], a, sl);
                sl = fmaf(c_RH[t], bq, sl);
                sh = fmaf(c_RL[t], cc2, sh);
                sh = fmaf(c_RH[t], d, sh);
            }
        }
        sL[r * Q + cl] = sl;
        sH[r * Q + cl] = sh;
    }
    __syncthreads();
    // row-idwt: out[j][c]
    for (int s = tid; s < H * Q; s += 256) {
        int j = s / Q, cl = s - j * Q;
        float v = 0.f;
        int t0 = (j & 1) ^ 1;
        #pragma unroll
        for (int t = t0; t < 16; t += 2) {
            int i = (j + 7 - t) >> 1;
            if (i >= 0 && i < h) {
                v = fmaf(c_RL[t], sL[i * Q + cl], v);
                v = fmaf(c_RH[t], sH[i * Q + cl], v);
            }
        }
        long o = (long)img * H * W + (long)j * W + q0 + cl;
        if (fin) outbf[o] = f2bf(v);
        else outp[o] = v;
    }
}

// Per-row median-low of |HH|: block=256 covers 256/w rows, padded LDS slices.
__global__ __launch_bounds__(256) void k_median256(const float* __restrict__ HH,
    float* __restrict__ thr, int w, int wsh, float scale)
{
    __shared__ float sm[256 + 8];
    int tid = threadIdx.x;
    int rloc = tid >> wsh;
    int j = tid & (w - 1);
    int rpb = 256 >> wsh;
    long row = (long)blockIdx.x * rpb + rloc;
    float v = fabsf(HH[row * w + j]);
    sm[rloc * (w + 1) + j] = v;
    __syncthreads();
    int k = (w - 1) >> 1;
    const float* base = sm + rloc * (w + 1);
    int lt = 0, eq = 0;
    for (int i = 0; i < w; ++i) {
        float u = base[i];
        lt += (u < v) ? 1 : 0;
        eq += (u == v) ? 1 : 0;
    }
    if (lt <= k && k < lt + eq) thr[row] = v * scale;
}

// Sliding-window register conv: thread = (img, band, row-half, col-quad).
__global__ __launch_bounds__(256) void k_incept_v2(const float* __restrict__ bands,
    const float* __restrict__ thrp, const float* __restrict__ comb,
    float* __restrict__ oLL, float* __restrict__ oLH,
    float* __restrict__ oHL, float* __restrict__ oHH,
    int h, int w, int nq_sh)
{
    int t = blockIdx.x * 256 + threadIdx.x;
    int q = t & ((1 << nq_sh) - 1);
    int rest = t >> nq_sh;
    int strip = rest & 1;
    int bi = rest >> 1;
    int band = bi & 3;
    int img = bi >> 2;
    long S = (long)NIMG * h * w;
    const float* in = bands + (long)band * S + (long)img * h * w;
    float* outp = (band == 0 ? oLL : band == 1 ? oLH : band == 2 ? oHL : oHH)
                  + (long)img * h * w;
    const float* trow = thrp + (long)img * h;
    float tmul = (band == 0) ? 0.f : 1.f;
    int rp2 = h >> 1;
    int ys = strip * rp2;
    int x0 = q << 2;
    float cb = comb[121];

    float okm[14]; int xa[14];
    #pragma unroll
    for (int j = 0; j < 14; ++j) {
        int x = x0 - 5 + j;
        okm[j] = (x >= 0 && x < w) ? 1.f : 0.f;
        xa[j] = (x < 0) ? 0 : ((x >= w) ? (w - 1) : x);
    }

    float acc[11][4];
    #pragma unroll
    for (int j = 0; j < 11; ++j) {
        acc[j][0] = 0.f; acc[j][1] = 0.f; acc[j][2] = 0.f; acc[j][3] = 0.f;
    }

    const float* rp = in + (long)(ys - 5) * w;
    int nrow = rp2 + 10;
    for (int i = 0; i < nrow; ++i) {
        int gy = ys - 5 + i;
        float buf[14];
        if (gy >= 0 && gy < h) {
            float th = trow[gy] * tmul;
            #pragma unroll
            for (int j = 0; j < 14; ++j) {
                float v = rp[xa[j]];
                float m = fabsf(v) - th;
                v = (m > 0.f) ? copysignf(m, v) : 0.f;
                buf[j] = v * okm[j];
            }
        } else {
            #pragma unroll
            for (int j = 0; j < 14; ++j) buf[j] = 0.f;
        }
        #pragma unroll
        for (int ky = 0; ky < 11; ++ky) {
            int jj = 10 - ky;
            #pragma unroll
            for (int kx = 0; kx < 11; ++kx) {
                float c = comb[ky * 11 + kx];
                acc[jj][0] = fmaf(buf[kx],     c, acc[jj][0]);
                acc[jj][1] = fmaf(buf[kx + 1], c, acc[jj][1]);
                acc[jj][2] = fmaf(buf[kx + 2], c, acc[jj][2]);
                acc[jj][3] = fmaf(buf[kx + 3], c, acc[jj][3]);
            }
        }
        if (i >= 10) {
            int oy = gy - 5;
            float4 st = make_float4(acc[0][0] + cb, acc[0][1] + cb,
                                    acc[0][2] + cb, acc[0][3] + cb);
            *(float4*)&outp[(long)oy * w + x0] = st;
        }
        #pragma unroll
        for (int j2 = 0; j2 < 10; ++j2) {
            acc[j2][0] = acc[j2 + 1][0]; acc[j2][1] = acc[j2 + 1][1];
            acc[j2][2] = acc[j2 + 1][2]; acc[j2][3] = acc[j2 + 1][3];
        }
        acc[10][0] = 0.f; acc[10][1] = 0.f; acc[10][2] = 0.f; acc[10][3] = 0.f;
        rp += w;
    }
}

// bf16 MFMA GEMM: out[m,d] = sum_k A[m,k]*W[d,k] + bias[d], scattered output.
__global__ __launch_bounds__(256) void k_gemm_bf16(const ushort_t* __restrict__ A,
    const ushort_t* __restrict__ Bw, const float* __restrict__ bias,
    float* __restrict__ out)
{
    __shared__ uint4 Al4[128 * 8];
    __shared__ uint4 Bl4[128 * 8];
    int m0 = blockIdx.x * 128, n0 = blockIdx.y * 128;
    int tid = threadIdx.x;
    int wid = tid >> 6, lane = tid & 63;
    int wr = wid >> 1, wc = wid & 1;
    f32x4 acc[4][4];
    #pragma unroll
    for (int a = 0; a < 4; ++a)
        #pragma unroll
        for (int b = 0; b < 4; ++b)
            acc[a][b] = (f32x4){0.f, 0.f, 0.f, 0.f};

    const uint4* Ag = (const uint4*)A;
    const uint4* Bg = (const uint4*)Bw;
    int row = tid >> 1, half = tid & 1;

    for (int k0 = 0; k0 < 256; k0 += 64) {
        int gca = ((m0 + row) * 256 + k0 + half * 32) >> 3;
        int gcb = ((n0 + row) * 256 + k0 + half * 32) >> 3;
        #pragma unroll
        for (int q = 0; q < 4; ++q) {
            int c = half * 4 + q;
            int sw = c ^ (row & 7);
            Al4[row * 8 + sw] = Ag[gca + q];
            Bl4[row * 8 + sw] = Bg[gcb + q];
        }
        __syncthreads();
        #pragma unroll
        for (int ks = 0; ks < 2; ++ks) {
            short8 af[4], bfr[4];
            int kc = ks * 4 + (lane >> 4);
            #pragma unroll
            for (int mi = 0; mi < 4; ++mi) {
                int r = wr * 64 + mi * 16 + (lane & 15);
                af[mi] = *(const short8*)&Al4[r * 8 + (kc ^ (r & 7))];
            }
            #pragma unroll
            for (int ni = 0; ni < 4; ++ni) {
                int r = wc * 64 + ni * 16 + (lane & 15);
                bfr[ni] = *(const short8*)&Bl4[r * 8 + (kc ^ (r & 7))];
            }
            #pragma unroll
            for (int mi = 0; mi < 4; ++mi)
                #pragma unroll
                for (int ni = 0; ni < 4; ++ni)
                    acc[mi][ni] = __builtin_amdgcn_mfma_f32_16x16x32_bf16(
                        af[mi], bfr[ni], acc[mi][ni], 0, 0, 0);
        }
        __syncthreads();
    }

    #pragma unroll
    for (int ni = 0; ni < 4; ++ni) {
        int d = n0 + wc * 64 + ni * 16 + (lane & 15);
        float bv = bias[d];
        #pragma unroll
        for (int mi = 0; mi < 4; ++mi) {
            #pragma unroll
            for (int r = 0; r < 4; ++r) {
                int m = m0 + wr * 64 + mi * 16 + (lane >> 4) * 4 + r;
                int img = m >> 7, t = m & 127;
                int bb = img / 100, nn = img - bb * 100;
                long ob = (((long)bb * T_DIM + t) * N_DIM + nn) * D_DIM + d;
                out[ob] = acc[mi][ni][r] + bv;
            }
        }
    }
}

extern "C" void kernel_launch(void* const* d_in, const int* in_sizes, int n_in,
                              void* d_out, int out_size, void* d_ws, size_t ws_size,
                              hipStream_t stream)
{
    const float* x = (const float*)d_in[0];
    const float* w0 = (const float*)d_in[2];  const float* b0 = (const float*)d_in[3];
    const float* w1 = (const float*)d_in[4];  const float* b1 = (const float*)d_in[5];
    const float* w2 = (const float*)d_in[6];  const float* b2 = (const float*)d_in[7];
    const float* w3 = (const float*)d_in[8];  const float* b3 = (const float*)d_in[9];
    const float* w4 = (const float*)d_in[10]; const float* b4 = (const float*)d_in[11];
    const float* w5 = (const float*)d_in[12]; const float* b5 = (const float*)d_in[13];
    const float* out_w = (const float*)d_in[14];
    const float* out_b = (const float*)d_in[15];
    float* ws = (float*)d_ws;
    float* outp = (float*)d_out;

    const long S0 = 6553600, S1 = 1638400, S2 = 409600;
    const long RT = 13107200;

    float* pLH[3] = { ws,               ws + 3 * S0,           ws + 3 * S0 + 3 * S1 };
    float* pHL[3] = { ws + S0,          ws + 3 * S0 + S1,      ws + 3 * S0 + 3 * S1 + S2 };
    float* pHH[3] = { ws + 2 * S0,      ws + 3 * S0 + 2 * S1,  ws + 3 * S0 + 3 * S1 + 2 * S2 };
    float* pLL2 = ws + 3 * S0 + 3 * S1 + 3 * S2;
    float* comb = ws + 3 * S0 + 3 * S1 + 4 * S2;
    float* thr  = comb + 128;
    float* wbf_f = thr + 51200;
    float* LLa  = wbf_f + 32768;
    float* LLb  = LLa + S0;
    float* bufA = LLb + S1;
    float* bufLL = bufA + RT;            // subband scratch + idwt outputs
    ushort_t* wbf = (ushort_t*)wbf_f;
    ushort_t* Abf = (ushort_t*)bufA;     // final idwt output (bf16), 52 MB
    float* idwt_out2 = bufLL;            // 800*32*64
    float* idwt_out1 = bufLL + S2 * 4;   // 800*64*128 (past L2 out)
    (void)ws_size; (void)in_sizes; (void)n_in; (void)out_size;

    hipLaunchKernelGGL(k_build_comb, dim3(1), dim3(128), 0, stream,
                       w0, w1, w2, w3, w4, w5, b0, b1, b2, b3, b4, b5, comb);
    hipLaunchKernelGGL(k_cvt_bf16, dim3(256), dim3(256), 0, stream, out_w, wbf, 65536);

    float thr_scale = (float)(sqrt(2.0 * log(128.0)) / 0.6745);

    int Hs[3] = {128, 64, 32}, Ws3[3] = {256, 128, 64};
    int wsh3[3] = {7, 6, 5};      // log2(w)
    int nqsh3[3] = {5, 4, 3};     // log2(w/4)
    int Qd[3] = {32, 64, 32};     // dwt strip widths (w/Q strips)
    const float* curLL = x;
    float* convLLout[3] = { LLa, LLb, pLL2 };

    for (int lev = 0; lev < 3; ++lev) {
        int H = Hs[lev], W = Ws3[lev], h = H >> 1, w = W >> 1;
        long S = (long)NIMG * h * w;
        float* rLL = bufLL;
        float* rHH = bufLL + 3 * S;
        int nstrips = w / Qd[lev];
        hipLaunchKernelGGL(k_dwt2d, dim3(NIMG * nstrips), dim3(256), 0, stream,
                           curLL, rLL, bufLL + S, bufLL + 2 * S, rHH,
                           H, W, Qd[lev], lev == 0 ? 1 : 0);
        hipLaunchKernelGGL(k_median256, dim3((int)(S / 256)), dim3(256), 0, stream,
                           rHH, thr, w, wsh3[lev], thr_scale);
        int nthr = NIMG * 4 * 2 * (w / 4);
        hipLaunchKernelGGL(k_incept_v2, dim3(nthr / 256), dim3(256), 0, stream,
                           rLL, thr, comb, convLLout[lev], pLH[lev], pHL[lev], pHH[lev],
                           h, w, nqsh3[lev]);
        curLL = convLLout[lev];
    }

    // iDWT chain (fused per level)
    // L2: subbands (16x32) -> out 32x64
    hipLaunchKernelGGL(k_idwt2d, dim3(NIMG * (64 / 64)), dim3(256), 0, stream,
                       pLL2, pLH[2], pHL[2], pHH[2], idwt_out2, (ushort_t*)0, 32, 64, 0);
    // L1: subbands (32x64) -> out 64x128
    hipLaunchKernelGGL(k_idwt2d, dim3(NIMG * (128 / 64)), dim3(256), 0, stream,
                       idwt_out2, pLH[1], pHL[1], pHH[1], idwt_out1, (ushort_t*)0, 64, 128, 0);
    // L0: subbands (64x128) -> out 128x256 (bf16 for GEMM)
    hipLaunchKernelGGL(k_idwt2d, dim3(NIMG * (256 / 64)), dim3(256), 0, stream,
                       idwt_out1, pLH[0], pHL[0], pHH[0], (float*)0, Abf, 128, 256, 1);

    dim3 gg(102400 / 128, 2);
    hipLaunchKernelGGL(k_gemm_bf16, gg, dim3(256), 0, stream, Abf, wbf, out_b, outp);
}

// Round 5
// 1012.431 us; speedup vs baseline: 1.9113x; 1.3016x over previous
//
#include <hip/hip_runtime.h>
#include <math.h>

#define NIMG 800
#define T_DIM 128
#define N_DIM 100
#define D_DIM 256

typedef unsigned short ushort_t;
typedef unsigned int uint_t;
typedef __attribute__((ext_vector_type(8))) short short8;
typedef __attribute__((ext_vector_type(4))) float f32x4;

// REC_LO[t] = DEC_LO[15-t];  REC_HI[t] = DEC_LO[t] * (-1)^t
__constant__ float c_RL[16] = {
     0.05441584224308161,   0.3128715909144659,    0.6756307362980128,    0.5853546836548691,
    -0.015829105256023893, -0.2840155429624281,    0.00047248457399797254,0.128747426620186,
    -0.01736930100202211,  -0.04408825393106472,   0.013981027917015516,  0.008746094047015655,
    -0.00487035299301066,  -0.0003917403729959771, 0.0006754494059985568, -0.00011747678400228192
};
__constant__ float c_RH[16] = {
    -0.00011747678400228192,-0.0006754494059985568,-0.0003917403729959771, 0.00487035299301066,
     0.008746094047015655,  -0.013981027917015516, -0.04408825393106472,   0.01736930100202211,
     0.128747426620186,     -0.00047248457399797254,-0.2840155429624281,   0.015829105256023893,
     0.5853546836548691,    -0.6756307362980128,    0.3128715909144659,   -0.05441584224308161
};

__device__ inline ushort_t f2bf(float f) {
    uint_t u = __float_as_uint(f);
    uint_t r = (u + 0x7FFFu + ((u >> 16) & 1u)) >> 16;
    return (ushort_t)r;
}

// Build combined 11x11 inception kernel
__global__ void k_build_comb(const float* w0, const float* w1, const float* w2,
                             const float* w3, const float* w4, const float* w5,
                             const float* b0, const float* b1, const float* b2,
                             const float* b3, const float* b4, const float* b5,
                             float* comb)
{
    int t = threadIdx.x;
    const float* wp[6] = {w0, w1, w2, w3, w4, w5};
    if (t < 121) {
        int dy = t / 11 - 5, dx = t % 11 - 5;
        int ay = dy < 0 ? -dy : dy, ax = dx < 0 ? -dx : dx;
        int a = ay > ax ? ay : ax;
        float s = 0.f;
        for (int i = a; i < 6; ++i) {
            int k = 2 * i + 1;
            s += wp[i][(i + dy) * k + (i + dx)];
        }
        comb[t] = s * (1.0f / 6.0f);
    } else if (t == 121) {
        comb[121] = (b0[0] + b1[0] + b2[0] + b3[0] + b4[0] + b5[0]) * (1.0f / 6.0f);
    }
}

__global__ void k_cvt_bf16(const float* __restrict__ in, ushort_t* __restrict__ out, int n)
{
    int i = blockIdx.x * blockDim.x + threadIdx.x;
    if (i < n) out[i] = f2bf(in[i]);
}

// Fused per-level 2D DWT, row-tiled: block = (img, 16-row band, 32-col strip).
// LDS: xs[46][80] staged (zero-padded) -> row-pass Lp/Hp[2][16][40] (parity-split)
// -> col-pass -> 4 subbands. 24.9 KB LDS -> 6 blocks/CU. No per-tap branches.
__global__ __launch_bounds__(256) void k_dwt2d_v2(const float* __restrict__ in,
    float* __restrict__ LL, float* __restrict__ LH,
    float* __restrict__ HL, float* __restrict__ HH,
    int H, int W, int nrb, int nstrips, int level0)
{
    __shared__ float xs[46 * 80];
    __shared__ float Lp[2][16][40];
    __shared__ float Hp[2][16][40];
    int h = H >> 1, w = W >> 1;
    int bid = blockIdx.x;
    int per = nrb * nstrips;
    int img = bid / per;
    int rem = bid - img * per;
    int rb = rem / nstrips;
    int q = rem - rb * nstrips;
    int r0 = rb * 16, q0 = q * 32;
    int c0 = 2 * q0 - 7;
    int jbase = 2 * r0 - 7;
    int tid = threadIdx.x;

    const float* ip; long rstride;
    if (level0) {
        int bb = img / 100, nn = img - bb * 100;
        ip = in + (long)bb * (T_DIM * N_DIM * D_DIM) + (long)nn * D_DIM;
        rstride = (long)N_DIM * D_DIM;
    } else {
        ip = in + (long)img * H * W;
        rstride = W;
    }

    for (int s = tid; s < 46 * 80; s += 256) {
        int jl = s / 80, c = s - jl * 80;
        int gj = jbase + jl, gc = c0 + c;
        float v = 0.f;
        if (gj >= 0 && gj < H && gc >= 0 && gc < W)
            v = ip[(long)gj * rstride + gc];
        xs[s] = v;
    }
    __syncthreads();

    // row pass: Lp[i][c] = sum_t RL[t] * xs[2*il + t][c]
    for (int s = tid; s < 16 * 80; s += 256) {
        int il = s / 80, c = s - il * 80;
        const float* base = xs + 2 * il * 80 + c;
        float sl = 0.f, sh = 0.f;
        #pragma unroll
        for (int t = 0; t < 16; ++t) {
            float v = base[t * 80];
            sl = fmaf(c_RL[t], v, sl);
            sh = fmaf(c_RH[t], v, sh);
        }
        Lp[c & 1][il][c >> 1] = sl;
        Hp[c & 1][il][c >> 1] = sh;
    }
    __syncthreads();

    // col pass: out[r][cc] = sum_t F[t] * Lp/Hp[r][2*cl + t]
    for (int s = tid; s < 16 * 32; s += 256) {
        int rl = s >> 5, cl = s & 31;
        float ll = 0.f, lh = 0.f, hl = 0.f, hh = 0.f;
        #pragma unroll
        for (int t = 0; t < 16; ++t) {
            float a = Lp[t & 1][rl][cl + (t >> 1)];
            float b = Hp[t & 1][rl][cl + (t >> 1)];
            ll = fmaf(c_RL[t], a, ll);
            lh = fmaf(c_RH[t], a, lh);
            hl = fmaf(c_RL[t], b, hl);
            hh = fmaf(c_RH[t], b, hh);
        }
        long o = (long)img * h * w + (long)(r0 + rl) * w + (q0 + cl);
        LL[o] = ll; LH[o] = lh; HL[o] = hl; HH[o] = hh;
    }
}

// Fused per-level 2D iDWT: block = (img, output-col strip of Q=64).
__global__ __launch_bounds__(256) void k_idwt2d(const float* __restrict__ LLp,
    const float* __restrict__ LHp, const float* __restrict__ HLp,
    const float* __restrict__ HHp, float* __restrict__ outp,
    ushort_t* __restrict__ outbf, int H, int W, int fin)
{
    const int Q = 64;
    __shared__ float sm[18432];
    int h = H >> 1, w = W >> 1;
    int nstrips = W / Q;
    int img = blockIdx.x / nstrips;
    int q = blockIdx.x - img * nstrips;
    int q0 = q * Q;
    int i0 = (q0 >> 1) - 4;
    int SW = (Q >> 1) + 8;   // 40
    float* sLL = sm;
    float* sLH = sLL + h * SW;
    float* sHL = sLH + h * SW;
    float* sHH = sHL + h * SW;
    float* sL  = sHH + h * SW;
    float* sH  = sL + h * Q;
    int tid = threadIdx.x;

    long ibase = (long)img * h * w;
    for (int s = tid; s < h * SW; s += 256) {
        int r = s / SW, c = s - r * SW;
        int gc = i0 + c;
        bool ok = (gc >= 0 && gc < w);
        long o = ibase + (long)r * w + gc;
        sLL[s] = ok ? LLp[o] : 0.f;
        sLH[s] = ok ? LHp[o] : 0.f;
        sHL[s] = ok ? HLp[o] : 0.f;
        sHH[s] = ok ? HHp[o] : 0.f;
    }
    __syncthreads();
    for (int s = tid; s < h * Q; s += 256) {
        int r = s / Q, cl = s - r * Q;
        int c = q0 + cl;
        float sl = 0.f, sh = 0.f;
        int t0 = (c & 1) ^ 1;
        #pragma unroll
        for (int t = t0; t < 16; t += 2) {
            int i = (c + 7 - t) >> 1;
            if (i >= 0 && i < w) {
                int lc = i - i0;
                float a = sLL[r * SW + lc], bq = sLH[r * SW + lc];
                float cc2 = sHL[r * SW + lc], d = sHH[r * SW + lc];
                sl = fmaf(c_RL[t], a, sl);
                sl = fmaf(c_RH[t], bq, sl);
                sh = fmaf(c_RL[t], cc2, sh);
                sh = fmaf(c_RH[t], d, sh);
            }
        }
        sL[r * Q + cl] = sl;
        sH[r * Q + cl] = sh;
    }
    __syncthreads();
    for (int s = tid; s < H * Q; s += 256) {
        int j = s / Q, cl = s - j * Q;
        float v = 0.f;
        int t0 = (j & 1) ^ 1;
        #pragma unroll
        for (int t = t0; t < 16; t += 2) {
            int i = (j + 7 - t) >> 1;
            if (i >= 0 && i < h) {
                v = fmaf(c_RL[t], sL[i * Q + cl], v);
                v = fmaf(c_RH[t], sH[i * Q + cl], v);
            }
        }
        long o = (long)img * H * W + (long)j * W + q0 + cl;
        if (fin) outbf[o] = f2bf(v);
        else outp[o] = v;
    }
}

// Per-row median-low of |HH|: block=256 covers 256/w rows, padded LDS slices.
__global__ __launch_bounds__(256) void k_median256(const float* __restrict__ HH,
    float* __restrict__ thr, int w, int wsh, float scale)
{
    __shared__ float sm[256 + 8];
    int tid = threadIdx.x;
    int rloc = tid >> wsh;
    int j = tid & (w - 1);
    int rpb = 256 >> wsh;
    long row = (long)blockIdx.x * rpb + rloc;
    float v = fabsf(HH[row * w + j]);
    sm[rloc * (w + 1) + j] = v;
    __syncthreads();
    int k = (w - 1) >> 1;
    const float* base = sm + rloc * (w + 1);
    int lt = 0, eq = 0;
    for (int i = 0; i < w; ++i) {
        float u = base[i];
        lt += (u < v) ? 1 : 0;
        eq += (u == v) ? 1 : 0;
    }
    if (lt <= k && k < lt + eq) thr[row] = v * scale;
}

// Sliding-window register conv: thread = (img, band, row-half, col-quad).
__global__ __launch_bounds__(256) void k_incept_v2(const float* __restrict__ bands,
    const float* __restrict__ thrp, const float* __restrict__ comb,
    float* __restrict__ oLL, float* __restrict__ oLH,
    float* __restrict__ oHL, float* __restrict__ oHH,
    int h, int w, int nq_sh)
{
    int t = blockIdx.x * 256 + threadIdx.x;
    int q = t & ((1 << nq_sh) - 1);
    int rest = t >> nq_sh;
    int strip = rest & 1;
    int bi = rest >> 1;
    int band = bi & 3;
    int img = bi >> 2;
    long S = (long)NIMG * h * w;
    const float* in = bands + (long)band * S + (long)img * h * w;
    float* outp = (band == 0 ? oLL : band == 1 ? oLH : band == 2 ? oHL : oHH)
                  + (long)img * h * w;
    const float* trow = thrp + (long)img * h;
    float tmul = (band == 0) ? 0.f : 1.f;
    int rp2 = h >> 1;
    int ys = strip * rp2;
    int x0 = q << 2;
    float cb = comb[121];

    float okm[14]; int xa[14];
    #pragma unroll
    for (int j = 0; j < 14; ++j) {
        int x = x0 - 5 + j;
        okm[j] = (x >= 0 && x < w) ? 1.f : 0.f;
        xa[j] = (x < 0) ? 0 : ((x >= w) ? (w - 1) : x);
    }

    float acc[11][4];
    #pragma unroll
    for (int j = 0; j < 11; ++j) {
        acc[j][0] = 0.f; acc[j][1] = 0.f; acc[j][2] = 0.f; acc[j][3] = 0.f;
    }

    const float* rp = in + (long)(ys - 5) * w;
    int nrow = rp2 + 10;
    for (int i = 0; i < nrow; ++i) {
        int gy = ys - 5 + i;
        float buf[14];
        if (gy >= 0 && gy < h) {
            float th = trow[gy] * tmul;
            #pragma unroll
            for (int j = 0; j < 14; ++j) {
                float v = rp[xa[j]];
                float m = fabsf(v) - th;
                v = (m > 0.f) ? copysignf(m, v) : 0.f;
                buf[j] = v * okm[j];
            }
        } else {
            #pragma unroll
            for (int j = 0; j < 14; ++j) buf[j] = 0.f;
        }
        #pragma unroll
        for (int ky = 0; ky < 11; ++ky) {
            int jj = 10 - ky;
            #pragma unroll
            for (int kx = 0; kx < 11; ++kx) {
                float c = comb[ky * 11 + kx];
                acc[jj][0] = fmaf(buf[kx],     c, acc[jj][0]);
                acc[jj][1] = fmaf(buf[kx + 1], c, acc[jj][1]);
                acc[jj][2] = fmaf(buf[kx + 2], c, acc[jj][2]);
                acc[jj][3] = fmaf(buf[kx + 3], c, acc[jj][3]);
            }
        }
        if (i >= 10) {
            int oy = gy - 5;
            float4 st = make_float4(acc[0][0] + cb, acc[0][1] + cb,
                                    acc[0][2] + cb, acc[0][3] + cb);
            *(float4*)&outp[(long)oy * w + x0] = st;
        }
        #pragma unroll
        for (int j2 = 0; j2 < 10; ++j2) {
            acc[j2][0] = acc[j2 + 1][0]; acc[j2][1] = acc[j2 + 1][1];
            acc[j2][2] = acc[j2 + 1][2]; acc[j2][3] = acc[j2 + 1][3];
        }
        acc[10][0] = 0.f; acc[10][1] = 0.f; acc[10][2] = 0.f; acc[10][3] = 0.f;
        rp += w;
    }
}

// bf16 MFMA GEMM: out[m,d] = sum_k A[m,k]*W[d,k] + bias[d], scattered output.
__global__ __launch_bounds__(256) void k_gemm_bf16(const ushort_t* __restrict__ A,
    const ushort_t* __restrict__ Bw, const float* __restrict__ bias,
    float* __restrict__ out)
{
    __shared__ uint4 Al4[128 * 8];
    __shared__ uint4 Bl4[128 * 8];
    int m0 = blockIdx.x * 128, n0 = blockIdx.y * 128;
    int tid = threadIdx.x;
    int wid = tid >> 6, lane = tid & 63;
    int wr = wid >> 1, wc = wid & 1;
    f32x4 acc[4][4];
    #pragma unroll
    for (int a = 0; a < 4; ++a)
        #pragma unroll
        for (int b = 0; b < 4; ++b)
            acc[a][b] = (f32x4){0.f, 0.f, 0.f, 0.f};

    const uint4* Ag = (const uint4*)A;
    const uint4* Bg = (const uint4*)Bw;
    int row = tid >> 1, half = tid & 1;

    for (int k0 = 0; k0 < 256; k0 += 64) {
        int gca = ((m0 + row) * 256 + k0 + half * 32) >> 3;
        int gcb = ((n0 + row) * 256 + k0 + half * 32) >> 3;
        #pragma unroll
        for (int q = 0; q < 4; ++q) {
            int c = half * 4 + q;
            int sw = c ^ (row & 7);
            Al4[row * 8 + sw] = Ag[gca + q];
            Bl4[row * 8 + sw] = Bg[gcb + q];
        }
        __syncthreads();
        #pragma unroll
        for (int ks = 0; ks < 2; ++ks) {
            short8 af[4], bfr[4];
            int kc = ks * 4 + (lane >> 4);
            #pragma unroll
            for (int mi = 0; mi < 4; ++mi) {
                int r = wr * 64 + mi * 16 + (lane & 15);
                af[mi] = *(const short8*)&Al4[r * 8 + (kc ^ (r & 7))];
            }
            #pragma unroll
            for (int ni = 0; ni < 4; ++ni) {
                int r = wc * 64 + ni * 16 + (lane & 15);
                bfr[ni] = *(const short8*)&Bl4[r * 8 + (kc ^ (r & 7))];
            }
            #pragma unroll
            for (int mi = 0; mi < 4; ++mi)
                #pragma unroll
                for (int ni = 0; ni < 4; ++ni)
                    acc[mi][ni] = __builtin_amdgcn_mfma_f32_16x16x32_bf16(
                        af[mi], bfr[ni], acc[mi][ni], 0, 0, 0);
        }
        __syncthreads();
    }

    #pragma unroll
    for (int ni = 0; ni < 4; ++ni) {
        int d = n0 + wc * 64 + ni * 16 + (lane & 15);
        float bv = bias[d];
        #pragma unroll
        for (int mi = 0; mi < 4; ++mi) {
            #pragma unroll
            for (int r = 0; r < 4; ++r) {
                int m = m0 + wr * 64 + mi * 16 + (lane >> 4) * 4 + r;
                int img = m >> 7, t = m & 127;
                int bb = img / 100, nn = img - bb * 100;
                long ob = (((long)bb * T_DIM + t) * N_DIM + nn) * D_DIM + d;
                out[ob] = acc[mi][ni][r] + bv;
            }
        }
    }
}

extern "C" void kernel_launch(void* const* d_in, const int* in_sizes, int n_in,
                              void* d_out, int out_size, void* d_ws, size_t ws_size,
                              hipStream_t stream)
{
    const float* x = (const float*)d_in[0];
    const float* w0 = (const float*)d_in[2];  const float* b0 = (const float*)d_in[3];
    const float* w1 = (const float*)d_in[4];  const float* b1 = (const float*)d_in[5];
    const float* w2 = (const float*)d_in[6];  const float* b2 = (const float*)d_in[7];
    const float* w3 = (const float*)d_in[8];  const float* b3 = (const float*)d_in[9];
    const float* w4 = (const float*)d_in[10]; const float* b4 = (const float*)d_in[11];
    const float* w5 = (const float*)d_in[12]; const float* b5 = (const float*)d_in[13];
    const float* out_w = (const float*)d_in[14];
    const float* out_b = (const float*)d_in[15];
    float* ws = (float*)d_ws;
    float* outp = (float*)d_out;

    const long S0 = 6553600, S1 = 1638400, S2 = 409600;
    const long RT = 13107200;

    float* pLH[3] = { ws,               ws + 3 * S0,           ws + 3 * S0 + 3 * S1 };
    float* pHL[3] = { ws + S0,          ws + 3 * S0 + S1,      ws + 3 * S0 + 3 * S1 + S2 };
    float* pHH[3] = { ws + 2 * S0,      ws + 3 * S0 + 2 * S1,  ws + 3 * S0 + 3 * S1 + 2 * S2 };
    float* pLL2 = ws + 3 * S0 + 3 * S1 + 3 * S2;
    float* comb = ws + 3 * S0 + 3 * S1 + 4 * S2;
    float* thr  = comb + 128;
    float* wbf_f = thr + 51200;
    float* LLa  = wbf_f + 32768;
    float* LLb  = LLa + S0;
    float* bufA = LLb + S1;
    float* bufLL = bufA + RT;            // subband scratch + idwt outputs
    ushort_t* wbf = (ushort_t*)wbf_f;
    ushort_t* Abf = (ushort_t*)bufA;     // final idwt output (bf16), 52 MB
    float* idwt_out2 = bufLL;            // 800*32*64
    float* idwt_out1 = bufLL + S2 * 4;   // 800*64*128
    (void)ws_size; (void)in_sizes; (void)n_in; (void)out_size;

    hipLaunchKernelGGL(k_build_comb, dim3(1), dim3(128), 0, stream,
                       w0, w1, w2, w3, w4, w5, b0, b1, b2, b3, b4, b5, comb);
    hipLaunchKernelGGL(k_cvt_bf16, dim3(256), dim3(256), 0, stream, out_w, wbf, 65536);

    float thr_scale = (float)(sqrt(2.0 * log(128.0)) / 0.6745);

    int Hs[3] = {128, 64, 32}, Ws3[3] = {256, 128, 64};
    int wsh3[3] = {7, 6, 5};      // log2(w)
    int nqsh3[3] = {5, 4, 3};     // log2(w/4)
    const float* curLL = x;
    float* convLLout[3] = { LLa, LLb, pLL2 };

    for (int lev = 0; lev < 3; ++lev) {
        int H = Hs[lev], W = Ws3[lev], h = H >> 1, w = W >> 1;
        long S = (long)NIMG * h * w;
        float* rLL = bufLL;
        float* rHH = bufLL + 3 * S;
        int nrb = h / 16, nstrips = w / 32;
        if (nrb < 1) nrb = 1;
        if (nstrips < 1) nstrips = 1;
        hipLaunchKernelGGL(k_dwt2d_v2, dim3(NIMG * nrb * nstrips), dim3(256), 0, stream,
                           curLL, rLL, bufLL + S, bufLL + 2 * S, rHH,
                           H, W, nrb, nstrips, lev == 0 ? 1 : 0);
        hipLaunchKernelGGL(k_median256, dim3((int)(S / 256)), dim3(256), 0, stream,
                           rHH, thr, w, wsh3[lev], thr_scale);
        int nthr = NIMG * 4 * 2 * (w / 4);
        hipLaunchKernelGGL(k_incept_v2, dim3(nthr / 256), dim3(256), 0, stream,
                           rLL, thr, comb, convLLout[lev], pLH[lev], pHL[lev], pHH[lev],
                           h, w, nqsh3[lev]);
        curLL = convLLout[lev];
    }

    // iDWT chain (fused per level)
    hipLaunchKernelGGL(k_idwt2d, dim3(NIMG * (64 / 64)), dim3(256), 0, stream,
                       pLL2, pLH[2], pHL[2], pHH[2], idwt_out2, (ushort_t*)0, 32, 64, 0);
    hipLaunchKernelGGL(k_idwt2d, dim3(NIMG * (128 / 64)), dim3(256), 0, stream,
                       idwt_out2, pLH[1], pHL[1], pHH[1], idwt_out1, (ushort_t*)0, 64, 128, 0);
    hipLaunchKernelGGL(k_idwt2d, dim3(NIMG * (256 / 64)), dim3(256), 0, stream,
                       idwt_out1, pLH[0], pHL[0], pHH[0], (float*)0, Abf, 128, 256, 1);

    dim3 gg(102400 / 128, 2);
    hipLaunchKernelGGL(k_gemm_bf16, gg, dim3(256), 0, stream, Abf, wbf, out_b, outp);
}

// Round 6
// 811.248 us; speedup vs baseline: 2.3852x; 1.2480x over previous
//
#include <hip/hip_runtime.h>
#include <math.h>

#define NIMG 800
#define T_DIM 128
#define N_DIM 100
#define D_DIM 256

typedef unsigned short ushort_t;
typedef unsigned int uint_t;
typedef __attribute__((ext_vector_type(8))) short short8;
typedef __attribute__((ext_vector_type(4))) float f32x4;

// REC_LO[t] = DEC_LO[15-t];  REC_HI[t] = DEC_LO[t] * (-1)^t
__constant__ float c_RL[16] = {
     0.05441584224308161,   0.3128715909144659,    0.6756307362980128,    0.5853546836548691,
    -0.015829105256023893, -0.2840155429624281,    0.00047248457399797254,0.128747426620186,
    -0.01736930100202211,  -0.04408825393106472,   0.013981027917015516,  0.008746094047015655,
    -0.00487035299301066,  -0.0003917403729959771, 0.0006754494059985568, -0.00011747678400228192
};
__constant__ float c_RH[16] = {
    -0.00011747678400228192,-0.0006754494059985568,-0.0003917403729959771, 0.00487035299301066,
     0.008746094047015655,  -0.013981027917015516, -0.04408825393106472,   0.01736930100202211,
     0.128747426620186,     -0.00047248457399797254,-0.2840155429624281,   0.015829105256023893,
     0.5853546836548691,    -0.6756307362980128,    0.3128715909144659,   -0.05441584224308161
};

__device__ inline ushort_t f2bf(float f) {
    uint_t u = __float_as_uint(f);
    uint_t r = (u + 0x7FFFu + ((u >> 16) & 1u)) >> 16;
    return (ushort_t)r;
}

// Build combined 11x11 inception kernel
__global__ void k_build_comb(const float* w0, const float* w1, const float* w2,
                             const float* w3, const float* w4, const float* w5,
                             const float* b0, const float* b1, const float* b2,
                             const float* b3, const float* b4, const float* b5,
                             float* comb)
{
    int t = threadIdx.x;
    const float* wp[6] = {w0, w1, w2, w3, w4, w5};
    if (t < 121) {
        int dy = t / 11 - 5, dx = t % 11 - 5;
        int ay = dy < 0 ? -dy : dy, ax = dx < 0 ? -dx : dx;
        int a = ay > ax ? ay : ax;
        float s = 0.f;
        for (int i = a; i < 6; ++i) {
            int k = 2 * i + 1;
            s += wp[i][(i + dy) * k + (i + dx)];
        }
        comb[t] = s * (1.0f / 6.0f);
    } else if (t == 121) {
        comb[121] = (b0[0] + b1[0] + b2[0] + b3[0] + b4[0] + b5[0]) * (1.0f / 6.0f);
    }
}

__global__ void k_cvt_bf16(const float* __restrict__ in, ushort_t* __restrict__ out, int n)
{
    int i = blockIdx.x * blockDim.x + threadIdx.x;
    if (i < n) out[i] = f2bf(in[i]);
}

// Fused per-level 2D DWT, row-tiled: block = (img, 16-row band, 32-col strip).
__global__ __launch_bounds__(256) void k_dwt2d_v2(const float* __restrict__ in,
    float* __restrict__ LL, float* __restrict__ LH,
    float* __restrict__ HL, float* __restrict__ HH,
    int H, int W, int nrb, int nstrips, int level0)
{
    __shared__ float xs[46 * 80];
    __shared__ float Lp[2][16][40];
    __shared__ float Hp[2][16][40];
    int h = H >> 1, w = W >> 1;
    int bid = blockIdx.x;
    int per = nrb * nstrips;
    int img = bid / per;
    int rem = bid - img * per;
    int rb = rem / nstrips;
    int q = rem - rb * nstrips;
    int r0 = rb * 16, q0 = q * 32;
    int c0 = 2 * q0 - 7;
    int jbase = 2 * r0 - 7;
    int tid = threadIdx.x;

    const float* ip; long rstride;
    if (level0) {
        int bb = img / 100, nn = img - bb * 100;
        ip = in + (long)bb * (T_DIM * N_DIM * D_DIM) + (long)nn * D_DIM;
        rstride = (long)N_DIM * D_DIM;
    } else {
        ip = in + (long)img * H * W;
        rstride = W;
    }

    for (int s = tid; s < 46 * 80; s += 256) {
        int jl = s / 80, c = s - jl * 80;
        int gj = jbase + jl, gc = c0 + c;
        float v = 0.f;
        if (gj >= 0 && gj < H && gc >= 0 && gc < W)
            v = ip[(long)gj * rstride + gc];
        xs[s] = v;
    }
    __syncthreads();

    for (int s = tid; s < 16 * 80; s += 256) {
        int il = s / 80, c = s - il * 80;
        const float* base = xs + 2 * il * 80 + c;
        float sl = 0.f, sh = 0.f;
        #pragma unroll
        for (int t = 0; t < 16; ++t) {
            float v = base[t * 80];
            sl = fmaf(c_RL[t], v, sl);
            sh = fmaf(c_RH[t], v, sh);
        }
        Lp[c & 1][il][c >> 1] = sl;
        Hp[c & 1][il][c >> 1] = sh;
    }
    __syncthreads();

    for (int s = tid; s < 16 * 32; s += 256) {
        int rl = s >> 5, cl = s & 31;
        float ll = 0.f, lh = 0.f, hl = 0.f, hh = 0.f;
        #pragma unroll
        for (int t = 0; t < 16; ++t) {
            float a = Lp[t & 1][rl][cl + (t >> 1)];
            float b = Hp[t & 1][rl][cl + (t >> 1)];
            ll = fmaf(c_RL[t], a, ll);
            lh = fmaf(c_RH[t], a, lh);
            hl = fmaf(c_RL[t], b, hl);
            hh = fmaf(c_RH[t], b, hh);
        }
        long o = (long)img * h * w + (long)(r0 + rl) * w + (q0 + cl);
        LL[o] = ll; LH[o] = lh; HL[o] = hl; HH[o] = hh;
    }
}

// Fused per-level 2D iDWT, row-tiled: block = (img, 16-row band, 64-col strip).
// Stage 4 subband halo tiles (16x40 each, zero-padded) -> col-idwt sL/sH[16][64]
// -> row-idwt -> out. 18.4 KB LDS. All filter loops branchless.
__global__ __launch_bounds__(256) void k_idwt2d_v2(const float* __restrict__ LLp,
    const float* __restrict__ LHp, const float* __restrict__ HLp,
    const float* __restrict__ HHp, float* __restrict__ outp,
    ushort_t* __restrict__ outbf, int H, int W, int nrb, int nstrips, int fin)
{
    __shared__ float sub[4][16][40];
    __shared__ float sL[16][64];
    __shared__ float sH[16][64];
    int h = H >> 1, w = W >> 1;
    int bid = blockIdx.x;
    int per = nrb * nstrips;
    int img = bid / per;
    int rem = bid - img * per;
    int rb = rem / nstrips;
    int qs = rem - rb * nstrips;
    int j0 = rb * 16, q0 = qs * 64;
    int rbase = (j0 >> 1) - 4;
    int i0 = (q0 >> 1) - 4;
    int tid = threadIdx.x;
    long ibase = (long)img * h * w;

    for (int s = tid; s < 4 * 16 * 40; s += 256) {
        int b = s / 640;
        int r2 = s - b * 640;
        int r = r2 / 40, c = r2 - r * 40;
        int gr = rbase + r, gc = i0 + c;
        float v = 0.f;
        if (gr >= 0 && gr < h && gc >= 0 && gc < w) {
            const float* p = (b == 0) ? LLp : (b == 1) ? LHp : (b == 2) ? HLp : HHp;
            v = p[ibase + (long)gr * w + gc];
        }
        sub[b][r][c] = v;
    }
    __syncthreads();

    // col-idwt: sL/sH[r][cl] for the 64-col strip
    for (int s = tid; s < 16 * 64; s += 256) {
        int r = s >> 6, cl = s & 63;
        int c = q0 + cl;
        float sl = 0.f, sh = 0.f;
        int t0 = (c & 1) ^ 1;
        #pragma unroll
        for (int tt = 0; tt < 8; ++tt) {
            int t = t0 + 2 * tt;
            int lc = ((c + 7 - t) >> 1) - i0;
            sl = fmaf(c_RL[t], sub[0][r][lc], sl);
            sl = fmaf(c_RH[t], sub[1][r][lc], sl);
            sh = fmaf(c_RL[t], sub[2][r][lc], sh);
            sh = fmaf(c_RH[t], sub[3][r][lc], sh);
        }
        sL[r][cl] = sl;
        sH[r][cl] = sh;
    }
    __syncthreads();

    // row-idwt: out[j][c]
    for (int s = tid; s < 16 * 64; s += 256) {
        int jl = s >> 6, cl = s & 63;
        int j = j0 + jl;
        float v = 0.f;
        int t0 = (j & 1) ^ 1;
        #pragma unroll
        for (int tt = 0; tt < 8; ++tt) {
            int t = t0 + 2 * tt;
            int ir = ((j + 7 - t) >> 1) - rbase;
            v = fmaf(c_RL[t], sL[ir][cl], v);
            v = fmaf(c_RH[t], sH[ir][cl], v);
        }
        long o = (long)img * H * W + (long)j * W + q0 + cl;
        if (fin) outbf[o] = f2bf(v);
        else outp[o] = v;
    }
}

// Per-row median-low of |HH|: block=256 covers 256/w rows, padded LDS slices.
__global__ __launch_bounds__(256) void k_median256(const float* __restrict__ HH,
    float* __restrict__ thr, int w, int wsh, float scale)
{
    __shared__ float sm[256 + 8];
    int tid = threadIdx.x;
    int rloc = tid >> wsh;
    int j = tid & (w - 1);
    int rpb = 256 >> wsh;
    long row = (long)blockIdx.x * rpb + rloc;
    float v = fabsf(HH[row * w + j]);
    sm[rloc * (w + 1) + j] = v;
    __syncthreads();
    int k = (w - 1) >> 1;
    const float* base = sm + rloc * (w + 1);
    int lt = 0, eq = 0;
    for (int i = 0; i < w; ++i) {
        float u = base[i];
        lt += (u < v) ? 1 : 0;
        eq += (u == v) ? 1 : 0;
    }
    if (lt <= k && k < lt + eq) thr[row] = v * scale;
}

// Sliding-window register conv: thread = (img, band, row-half, col-quad).
__global__ __launch_bounds__(256) void k_incept_v2(const float* __restrict__ bands,
    const float* __restrict__ thrp, const float* __restrict__ comb,
    float* __restrict__ oLL, float* __restrict__ oLH,
    float* __restrict__ oHL, float* __restrict__ oHH,
    int h, int w, int nq_sh)
{
    int t = blockIdx.x * 256 + threadIdx.x;
    int q = t & ((1 << nq_sh) - 1);
    int rest = t >> nq_sh;
    int strip = rest & 1;
    int bi = rest >> 1;
    int band = bi & 3;
    int img = bi >> 2;
    long S = (long)NIMG * h * w;
    const float* in = bands + (long)band * S + (long)img * h * w;
    float* outp = (band == 0 ? oLL : band == 1 ? oLH : band == 2 ? oHL : oHH)
                  + (long)img * h * w;
    const float* trow = thrp + (long)img * h;
    float tmul = (band == 0) ? 0.f : 1.f;
    int rp2 = h >> 1;
    int ys = strip * rp2;
    int x0 = q << 2;
    float cb = comb[121];

    float okm[14]; int xa[14];
    #pragma unroll
    for (int j = 0; j < 14; ++j) {
        int x = x0 - 5 + j;
        okm[j] = (x >= 0 && x < w) ? 1.f : 0.f;
        xa[j] = (x < 0) ? 0 : ((x >= w) ? (w - 1) : x);
    }

    float acc[11][4];
    #pragma unroll
    for (int j = 0; j < 11; ++j) {
        acc[j][0] = 0.f; acc[j][1] = 0.f; acc[j][2] = 0.f; acc[j][3] = 0.f;
    }

    const float* rp = in + (long)(ys - 5) * w;
    int nrow = rp2 + 10;
    for (int i = 0; i < nrow; ++i) {
        int gy = ys - 5 + i;
        float buf[14];
        if (gy >= 0 && gy < h) {
            float th = trow[gy] * tmul;
            #pragma unroll
            for (int j = 0; j < 14; ++j) {
                float v = rp[xa[j]];
                float m = fabsf(v) - th;
                v = (m > 0.f) ? copysignf(m, v) : 0.f;
                buf[j] = v * okm[j];
            }
        } else {
            #pragma unroll
            for (int j = 0; j < 14; ++j) buf[j] = 0.f;
        }
        #pragma unroll
        for (int ky = 0; ky < 11; ++ky) {
            int jj = 10 - ky;
            #pragma unroll
            for (int kx = 0; kx < 11; ++kx) {
                float c = comb[ky * 11 + kx];
                acc[jj][0] = fmaf(buf[kx],     c, acc[jj][0]);
                acc[jj][1] = fmaf(buf[kx + 1], c, acc[jj][1]);
                acc[jj][2] = fmaf(buf[kx + 2], c, acc[jj][2]);
                acc[jj][3] = fmaf(buf[kx + 3], c, acc[jj][3]);
            }
        }
        if (i >= 10) {
            int oy = gy - 5;
            float4 st = make_float4(acc[0][0] + cb, acc[0][1] + cb,
                                    acc[0][2] + cb, acc[0][3] + cb);
            *(float4*)&outp[(long)oy * w + x0] = st;
        }
        #pragma unroll
        for (int j2 = 0; j2 < 10; ++j2) {
            acc[j2][0] = acc[j2 + 1][0]; acc[j2][1] = acc[j2 + 1][1];
            acc[j2][2] = acc[j2 + 1][2]; acc[j2][3] = acc[j2 + 1][3];
        }
        acc[10][0] = 0.f; acc[10][1] = 0.f; acc[10][2] = 0.f; acc[10][3] = 0.f;
        rp += w;
    }
}

// bf16 MFMA GEMM: out[m,d] = sum_k A[m,k]*W[d,k] + bias[d], scattered output.
__global__ __launch_bounds__(256) void k_gemm_bf16(const ushort_t* __restrict__ A,
    const ushort_t* __restrict__ Bw, const float* __restrict__ bias,
    float* __restrict__ out)
{
    __shared__ uint4 Al4[128 * 8];
    __shared__ uint4 Bl4[128 * 8];
    int m0 = blockIdx.x * 128, n0 = blockIdx.y * 128;
    int tid = threadIdx.x;
    int wid = tid >> 6, lane = tid & 63;
    int wr = wid >> 1, wc = wid & 1;
    f32x4 acc[4][4];
    #pragma unroll
    for (int a = 0; a < 4; ++a)
        #pragma unroll
        for (int b = 0; b < 4; ++b)
            acc[a][b] = (f32x4){0.f, 0.f, 0.f, 0.f};

    const uint4* Ag = (const uint4*)A;
    const uint4* Bg = (const uint4*)Bw;
    int row = tid >> 1, half = tid & 1;

    for (int k0 = 0; k0 < 256; k0 += 64) {
        int gca = ((m0 + row) * 256 + k0 + half * 32) >> 3;
        int gcb = ((n0 + row) * 256 + k0 + half * 32) >> 3;
        #pragma unroll
        for (int q = 0; q < 4; ++q) {
            int c = half * 4 + q;
            int sw = c ^ (row & 7);
            Al4[row * 8 + sw] = Ag[gca + q];
            Bl4[row * 8 + sw] = Bg[gcb + q];
        }
        __syncthreads();
        #pragma unroll
        for (int ks = 0; ks < 2; ++ks) {
            short8 af[4], bfr[4];
            int kc = ks * 4 + (lane >> 4);
            #pragma unroll
            for (int mi = 0; mi < 4; ++mi) {
                int r = wr * 64 + mi * 16 + (lane & 15);
                af[mi] = *(const short8*)&Al4[r * 8 + (kc ^ (r & 7))];
            }
            #pragma unroll
            for (int ni = 0; ni < 4; ++ni) {
                int r = wc * 64 + ni * 16 + (lane & 15);
                bfr[ni] = *(const short8*)&Bl4[r * 8 + (kc ^ (r & 7))];
            }
            #pragma unroll
            for (int mi = 0; mi < 4; ++mi)
                #pragma unroll
                for (int ni = 0; ni < 4; ++ni)
                    acc[mi][ni] = __builtin_amdgcn_mfma_f32_16x16x32_bf16(
                        af[mi], bfr[ni], acc[mi][ni], 0, 0, 0);
        }
        __syncthreads();
    }

    #pragma unroll
    for (int ni = 0; ni < 4; ++ni) {
        int d = n0 + wc * 64 + ni * 16 + (lane & 15);
        float bv = bias[d];
        #pragma unroll
        for (int mi = 0; mi < 4; ++mi) {
            #pragma unroll
            for (int r = 0; r < 4; ++r) {
                int m = m0 + wr * 64 + mi * 16 + (lane >> 4) * 4 + r;
                int img = m >> 7, t = m & 127;
                int bb = img / 100, nn = img - bb * 100;
                long ob = (((long)bb * T_DIM + t) * N_DIM + nn) * D_DIM + d;
                out[ob] = acc[mi][ni][r] + bv;
            }
        }
    }
}

extern "C" void kernel_launch(void* const* d_in, const int* in_sizes, int n_in,
                              void* d_out, int out_size, void* d_ws, size_t ws_size,
                              hipStream_t stream)
{
    const float* x = (const float*)d_in[0];
    const float* w0 = (const float*)d_in[2];  const float* b0 = (const float*)d_in[3];
    const float* w1 = (const float*)d_in[4];  const float* b1 = (const float*)d_in[5];
    const float* w2 = (const float*)d_in[6];  const float* b2 = (const float*)d_in[7];
    const float* w3 = (const float*)d_in[8];  const float* b3 = (const float*)d_in[9];
    const float* w4 = (const float*)d_in[10]; const float* b4 = (const float*)d_in[11];
    const float* w5 = (const float*)d_in[12]; const float* b5 = (const float*)d_in[13];
    const float* out_w = (const float*)d_in[14];
    const float* out_b = (const float*)d_in[15];
    float* ws = (float*)d_ws;
    float* outp = (float*)d_out;

    const long S0 = 6553600, S1 = 1638400, S2 = 409600;
    const long RT = 13107200;

    float* pLH[3] = { ws,               ws + 3 * S0,           ws + 3 * S0 + 3 * S1 };
    float* pHL[3] = { ws + S0,          ws + 3 * S0 + S1,      ws + 3 * S0 + 3 * S1 + S2 };
    float* pHH[3] = { ws + 2 * S0,      ws + 3 * S0 + 2 * S1,  ws + 3 * S0 + 3 * S1 + 2 * S2 };
    float* pLL2 = ws + 3 * S0 + 3 * S1 + 3 * S2;
    float* comb = ws + 3 * S0 + 3 * S1 + 4 * S2;
    float* thr  = comb + 128;
    float* wbf_f = thr + 51200;
    float* LLa  = wbf_f + 32768;
    float* LLb  = LLa + S0;
    float* bufA = LLb + S1;
    float* bufLL = bufA + RT;            // subband scratch + idwt outputs
    ushort_t* wbf = (ushort_t*)wbf_f;
    ushort_t* Abf = (ushort_t*)bufA;     // final idwt output (bf16), 52 MB
    float* idwt_out2 = bufLL;            // 800*32*64
    float* idwt_out1 = bufLL + S2 * 4;   // 800*64*128
    (void)ws_size; (void)in_sizes; (void)n_in; (void)out_size;

    hipLaunchKernelGGL(k_build_comb, dim3(1), dim3(128), 0, stream,
                       w0, w1, w2, w3, w4, w5, b0, b1, b2, b3, b4, b5, comb);
    hipLaunchKernelGGL(k_cvt_bf16, dim3(256), dim3(256), 0, stream, out_w, wbf, 65536);

    float thr_scale = (float)(sqrt(2.0 * log(128.0)) / 0.6745);

    int Hs[3] = {128, 64, 32}, Ws3[3] = {256, 128, 64};
    int wsh3[3] = {7, 6, 5};      // log2(w)
    int nqsh3[3] = {5, 4, 3};     // log2(w/4)
    const float* curLL = x;
    float* convLLout[3] = { LLa, LLb, pLL2 };

    for (int lev = 0; lev < 3; ++lev) {
        int H = Hs[lev], W = Ws3[lev], h = H >> 1, w = W >> 1;
        long S = (long)NIMG * h * w;
        float* rLL = bufLL;
        float* rHH = bufLL + 3 * S;
        int nrb = h / 16, nstrips = w / 32;
        if (nrb < 1) nrb = 1;
        if (nstrips < 1) nstrips = 1;
        hipLaunchKernelGGL(k_dwt2d_v2, dim3(NIMG * nrb * nstrips), dim3(256), 0, stream,
                           curLL, rLL, bufLL + S, bufLL + 2 * S, rHH,
                           H, W, nrb, nstrips, lev == 0 ? 1 : 0);
        hipLaunchKernelGGL(k_median256, dim3((int)(S / 256)), dim3(256), 0, stream,
                           rHH, thr, w, wsh3[lev], thr_scale);
        int nthr = NIMG * 4 * 2 * (w / 4);
        hipLaunchKernelGGL(k_incept_v2, dim3(nthr / 256), dim3(256), 0, stream,
                           rLL, thr, comb, convLLout[lev], pLH[lev], pHL[lev], pHH[lev],
                           h, w, nqsh3[lev]);
        curLL = convLLout[lev];
    }

    // iDWT chain (fused, row-tiled)
    hipLaunchKernelGGL(k_idwt2d_v2, dim3(NIMG * 2 * 1), dim3(256), 0, stream,
                       pLL2, pLH[2], pHL[2], pHH[2], idwt_out2, (ushort_t*)0,
                       32, 64, 2, 1, 0);
    hipLaunchKernelGGL(k_idwt2d_v2, dim3(NIMG * 4 * 2), dim3(256), 0, stream,
                       idwt_out2, pLH[1], pHL[1], pHH[1], idwt_out1, (ushort_t*)0,
                       64, 128, 4, 2, 0);
    hipLaunchKernelGGL(k_idwt2d_v2, dim3(NIMG * 8 * 4), dim3(256), 0, stream,
                       idwt_out1, pLH[0], pHL[0], pHH[0], (float*)0, Abf,
                       128, 256, 8, 4, 1);

    dim3 gg(102400 / 128, 2);
    hipLaunchKernelGGL(k_gemm_bf16, gg, dim3(256), 0, stream, Abf, wbf, out_b, outp);
}